// Round 11
// baseline (1051.244 us; speedup 1.0000x reference)
//
#include <hip/hip_runtime.h>
#include <math.h>

// Problem constants
#define B_     32
#define F_     64
#define T_     518
#define HID    64
#define GATES  256   // 4*HID
#define CCH    128   // 2*HID lstm output channels
#define NWAVE  6
#define WCH    768   // NWAVE*CCH
#define L2_    516   // T-2   (conv2 out)
#define L3_    512   // L2-4  (conv3 out)
#define L4_    510   // L3-2  (conv4/conv5 out)

typedef float v2f __attribute__((ext_vector_type(2)));
typedef _Float16 h2 __attribute__((ext_vector_type(2)));

__device__ __forceinline__ float frcp(float x) { return __builtin_amdgcn_rcpf(x); }
__device__ __forceinline__ float fsigmoid(float x) { return frcp(1.f + __expf(-x)); }
__device__ __forceinline__ float ftanh(float x) { return 1.f - 2.f * frcp(1.f + __expf(2.f * x)); }

__device__ __forceinline__ float fdot2(h2 a, h2 b, float c) {
#if __has_builtin(__builtin_amdgcn_fdot2)
    return __builtin_amdgcn_fdot2(a, b, c, false);
#else
    return fmaf((float)a[0], (float)b[0], fmaf((float)a[1], (float)b[1], c));
#endif
}

// ---------------------------------------------------------------------------
// K0: pack Whh (both dirs) to fp16 pairs. 1 block, 256 threads.
__global__ void packw_kernel(const float* __restrict__ whf, const float* __restrict__ whr,
                             h2* __restrict__ w16f, h2* __restrict__ w16r) {
    const int row = threadIdx.x;
    const float* sf = whf + (size_t)row * HID;
    const float* sr = whr + (size_t)row * HID;
#pragma unroll
    for (int i = 0; i < 32; ++i) {
        w16f[row * 32 + i] = (h2){(_Float16)sf[2 * i], (_Float16)sf[2 * i + 1]};
        w16r[row * 32 + i] = (h2){(_Float16)sr[2 * i], (_Float16)sr[2 * i + 1]};
    }
}

// ---------------------------------------------------------------------------
// K1: input projections, dir-split (grid z = dir) so each thread holds only
// 16 float4 of weights (64 VGPRs < remat threshold). Layout xg[t][p][u][g2].
__global__ void xg_kernel(const float* __restrict__ x,
                          const float* __restrict__ wif, const float* __restrict__ bf,
                          const float* __restrict__ wir, const float* __restrict__ br,
                          float* __restrict__ xg_f, float* __restrict__ xg_r,
                          float* __restrict__ stats, float* __restrict__ stats23) {
    if (blockIdx.x == 0 && blockIdx.y == 0 && blockIdx.z == 0) {
        for (int i = threadIdx.x; i < 2 * WCH; i += 256) stats[i] = 0.f;
        if (threadIdx.x < 320) stats23[threadIdx.x] = 0.f;   // 256 BN2 + 64 BN3
    }
    const int dir = blockIdx.z;
    const float* wi = dir ? wir : wif;
    const float* bi = dir ? br : bf;
    float* xgo = dir ? xg_r : xg_f;
    const int tid = threadIdx.x;
    const int wv  = tid >> 7;
    const int g2  = tid & 1;
    const int r   = (tid >> 1) & 63;
    const int g   = (2 * wv + g2) * 64 + r;       // gate row; store offset == tid
    const int b   = blockIdx.y;
    const int t0  = blockIdx.x * 8;
    float4 wa[16];
    const float4* w0 = (const float4*)(wi + g * F_);
#pragma unroll
    for (int i = 0; i < 16; ++i) wa[i] = w0[i];
    const float bv = bi[g];
    for (int tt = 0; tt < 8; ++tt) {
        const int t = t0 + tt;
        if (t >= T_) break;
        const float* xp = x + (size_t)b * F_ * T_ + t;
        float a0 = bv;
#pragma unroll
        for (int i = 0; i < 16; ++i) {
            float x0 = xp[(i * 4 + 0) * T_];
            float x1 = xp[(i * 4 + 1) * T_];
            float x2 = xp[(i * 4 + 2) * T_];
            float x3 = xp[(i * 4 + 3) * T_];
            a0 += wa[i].x * x0 + wa[i].y * x1 + wa[i].z * x2 + wa[i].w * x3;
        }
        xgo[((size_t)b * T_ + t) * GATES + tid] = a0;   // coalesced
    }
}

// ---------------------------------------------------------------------------
// K2: LSTM recurrence — UNIT-SPLIT 2-wave structure. Wave w owns units
// 32w..32w+31; lane half p = lane>>5 computes gate-pair (i,f) or (g,o) for
// unit u = 32w + (lane&31). Gate exchange = one __shfl_xor(.,32) instead of
// the old ds_write+barrier+ds_read round trip (R10 showed the step time is
// this serial chain, not weight bytes). h exchange via double-buffered
// hs16[2][64]: write buf s&1, read buf (s-1)&1 -> ONE barrier/step, no race.
// fp16 weights = 64 VGPRs/lane (below remat threshold). grid(64), block 128.
__global__ __launch_bounds__(128, 1) void lstm_kernel(
        const float* __restrict__ xgi_f, const float* __restrict__ xgi_r,
        const h2* __restrict__ w16f, const h2* __restrict__ w16r,
        float* __restrict__ X) {
    const int dir = blockIdx.x & 1;
    const int b   = blockIdx.x >> 1;
    const float* xg  = (dir ? xgi_r : xgi_f) + (size_t)b * T_ * GATES;
    const h2* w16 = dir ? w16r : w16f;
    const int tid = threadIdx.x;
    const int lw  = tid & 63;            // lane in wave
    const int w   = tid >> 6;            // wave id
    const int p   = lw >> 5;             // gate-pair: 0 -> (i,f), 1 -> (g,o)
    const int u   = 32 * w + (lw & 31);  // unit owned

    union U4 { uint4 u4; h2 h[4]; };
    U4 wA[8], wB[8];                     // rows (2p)*64+u and (2p+1)*64+u
    {
        const uint4* pA = (const uint4*)(w16 + (size_t)((2 * p) * HID + u) * 32);
        const uint4* pB = (const uint4*)(w16 + (size_t)((2 * p + 1) * HID + u) * 32);
#pragma unroll
        for (int i = 0; i < 8; ++i) { wA[i].u4 = pA[i]; wB[i].u4 = pB[i]; }
    }

    __shared__ __align__(16) _Float16 hs16[2][HID];   // double-buffered h
    if (lw < 32) { hs16[0][u] = (_Float16)0.f; hs16[1][u] = (_Float16)0.f; }
    float c = 0.f;
    float* Xrow = X + ((size_t)(b * CCH + dir * HID + u)) * T_;

    int t = dir ? (T_ - 1) : 0;
    const int step = dir ? -1 : 1;
    const float2* xg2 = (const float2*)xg;   // index (t*2 + p)*64 + u
    float2 q0 = xg2[((size_t)t * 2 + p) * 64 + u];
    float2 q1 = xg2[((size_t)(t + step) * 2 + p) * 64 + u];
    __syncthreads();

    for (int s = 0; s < T_; ++s) {
        const uint4* hp4 = (const uint4*)hs16[(s + 1) & 1];   // prev step's h
        float a0 = q0.x, a0b = 0.f;
        float a1 = q0.y, a1b = 0.f;
#pragma unroll
        for (int i = 0; i < 8; ++i) {
            U4 hv; hv.u4 = hp4[i];
            a0  = fdot2(wA[i].h[0], hv.h[0], a0);
            a0b = fdot2(wA[i].h[1], hv.h[1], a0b);
            a0  = fdot2(wA[i].h[2], hv.h[2], a0);
            a0b = fdot2(wA[i].h[3], hv.h[3], a0b);
            a1  = fdot2(wB[i].h[0], hv.h[0], a1);
            a1b = fdot2(wB[i].h[1], hv.h[1], a1b);
            a1  = fdot2(wB[i].h[2], hv.h[2], a1);
            a1b = fdot2(wB[i].h[3], hv.h[3], a1b);
        }
        const float gA = a0 + a0b;    // gate (2p)*64+u
        const float gB = a1 + a1b;    // gate (2p+1)*64+u
        const float oA = __shfl_xor(gA, 32, 64);
        const float oB = __shfl_xor(gB, 32, 64);
        const float gi = p ? oA : gA;
        const float gf = p ? oB : gB;
        const float gg = p ? gA : oA;
        const float go = p ? gB : oB;

        // prefetch next xg before the dependent tail
        int tp = t + 2 * step;
        tp = tp < 0 ? 0 : (tp >= T_ ? T_ - 1 : tp);
        const float2 qn = xg2[((size_t)tp * 2 + p) * 64 + u];

        const float si = fsigmoid(gi);
        const float sf = fsigmoid(gf);
        const float so = fsigmoid(go);
        c = sf * c + si * ftanh(gg);
        const float h = so * ftanh(c);

        if (lw < 32) { hs16[s & 1][u] = (_Float16)h; Xrow[t] = h; }
        asm volatile("s_waitcnt lgkmcnt(0)" ::: "memory");
        __builtin_amdgcn_s_barrier();

        q0 = q1; q1 = qn;
        t += step;
    }
}

// ---------------------------------------------------------------------------
// K3: wave module + fused BN1 partial stats. Chebyshev cos recurrence:
// 1 cos per (ii) instead of 7. grid(3, 128, 32), block 256
__global__ void wave_kernel(const float* __restrict__ X,
                            const float* __restrict__ bw, const float* __restrict__ bb,
                            float* __restrict__ wave, float* __restrict__ stats) {
    const int b = blockIdx.z, c = blockIdx.y;
    const int t0 = blockIdx.x * 256;
    const int tid = threadIdx.x;
    __shared__ float xs[256 + 14];
    __shared__ float bws[NWAVE][16];
    __shared__ float bbs[NWAVE];
    __shared__ float red[4][12];
    const float* xrow = X + ((size_t)(b * CCH + c)) * T_;
    for (int i = tid; i < 270; i += 256) {
        int tt = t0 - 7 + i;
        xs[i] = (tt >= 0 && tt < T_) ? xrow[tt] : 0.f;
    }
    if (tid < NWAVE * 15) bws[tid / 15][tid % 15] = bw[tid];
    if (tid < NWAVE) bbs[tid] = bb[tid];
    __syncthreads();
    const int t = t0 + tid;
    float ls[NWAVE], lq[NWAVE];
#pragma unroll
    for (int ii = 0; ii < NWAVE; ++ii) { ls[ii] = 0.f; lq[ii] = 0.f; }
    if (t < T_) {
        float win[15];
#pragma unroll
        for (int k = 0; k < 15; ++k) win[k] = xs[tid + k];
        float e[8];
        e[0] = win[7];
#pragma unroll
        for (int m = 1; m < 8; ++m) e[m] = win[7 - m] + win[7 + m];
        const float c0 = 6.28318530717958647692f / 15.f;  // 2*pi/WIDE
#pragma unroll
        for (int ii = 0; ii < NWAVE; ++ii) {
            float sc = bbs[ii];
#pragma unroll
            for (int k = 0; k < 15; ++k) sc += win[k] * bws[ii][k];
            sc = fmaxf(sc, 0.f);
            const float phi = c0 * (float)(ii + 1) * sc;
            const float c1 = __cosf(phi);
            float o = fmaf(e[1], c1, e[0]);
            float cp = 1.f, cc = c1;
#pragma unroll
            for (int m = 2; m < 8; ++m) {
                const float cn = fmaf(2.f * c1, cc, -cp);   // cos(m*phi)
                o = fmaf(e[m], cn, o);
                cp = cc; cc = cn;
            }
            const float q = (truncf(sc * 15.f) + 1.f) * (2.f / 17.f);
            const float val = o * rsqrtf(q);
            wave[((size_t)(b * WCH + ii * CCH + c)) * T_ + t] = val;
            ls[ii] = val;
            lq[ii] = val * val;
        }
    }
#pragma unroll
    for (int off = 32; off > 0; off >>= 1) {
#pragma unroll
        for (int ii = 0; ii < NWAVE; ++ii) {
            ls[ii] += __shfl_down(ls[ii], off);
            lq[ii] += __shfl_down(lq[ii], off);
        }
    }
    if ((tid & 63) == 0) {
        const int w = tid >> 6;
#pragma unroll
        for (int ii = 0; ii < NWAVE; ++ii) { red[w][ii] = ls[ii]; red[w][6 + ii] = lq[ii]; }
    }
    __syncthreads();
    if (tid < 12) {
        const float a = red[0][tid] + red[1][tid] + red[2][tid] + red[3][tid];
        const int ii = tid % 6;
        const int ch = ii * CCH + c;
        atomicAdd(&stats[(tid >= 6 ? WCH : 0) + ch], a);
    }
}

// Finalize BN1 stats: 1 block, 768 threads
__global__ void bn1_finalize_kernel(const float* __restrict__ stats,
                                    float* __restrict__ mean, float* __restrict__ rstd) {
    const int c = threadIdx.x;
    const float n = (float)(B_ * T_);
    const float m = stats[c] / n;
    const float v = stats[WCH + c] / n - m * m;
    mean[c] = m;
    rstd[c] = rsqrtf(v + 1e-5f);
}

// ---------------------------------------------------------------------------
// bnfold2: grid(128), block 256 (one block per output channel)
__global__ void bnfold2_kernel(const float* __restrict__ w2, const float* __restrict__ b2,
                               const float* __restrict__ m1, const float* __restrict__ r1,
                               const float* __restrict__ g1, const float* __restrict__ be1,
                               float* __restrict__ w2t, float* __restrict__ b2t) {
    const int o = blockIdx.x, tid = threadIdx.x;
    float part = 0.f;
    for (int idx = tid; idx < WCH * 3; idx += 256) {
        const int c = idx / 3;
        const float sc = r1[c] * g1[c];
        const float sh = be1[c] - m1[c] * sc;
        const float wv = w2[(size_t)o * (WCH * 3) + idx];
        w2t[(size_t)idx * 128 + o] = wv * sc;
        part += wv * sh;
    }
#pragma unroll
    for (int off = 32; off > 0; off >>= 1) part += __shfl_down(part, off);
    __shared__ float red[4];
    if ((tid & 63) == 0) red[tid >> 6] = part;
    __syncthreads();
    if (tid == 0) b2t[o] = b2[o] + red[0] + red[1] + red[2] + red[3];
}

// bnfold3 (BN2 finalize inline from raw stats2): grid(32), block 256
__global__ void bnfold3_kernel(const float* __restrict__ w3, const float* __restrict__ b3,
                               const float* __restrict__ stats2,
                               const float* __restrict__ g2, const float* __restrict__ be2,
                               float* __restrict__ w3t, float* __restrict__ b3t) {
    const int o = blockIdx.x, tid = threadIdx.x;
    __shared__ float sc2s[128], sh2s[128];
    if (tid < 128) {
        const float n = (float)(B_ * L2_);
        const float m = stats2[tid] / n;
        const float v = stats2[128 + tid] / n - m * m;
        const float sc = rsqrtf(v + 1e-5f) * g2[tid];
        sc2s[tid] = sc;
        sh2s[tid] = be2[tid] - m * sc;
    }
    __syncthreads();
    float part = 0.f;
    for (int idx = tid; idx < 128 * 5; idx += 256) {
        const int c = idx / 5;
        const float wv = w3[(size_t)o * 640 + idx];
        w3t[(size_t)idx * 32 + o] = wv * sc2s[c];
        part += wv * sh2s[c];
    }
#pragma unroll
    for (int off = 32; off > 0; off >>= 1) part += __shfl_down(part, off);
    __shared__ float red[4];
    if ((tid & 63) == 0) red[tid >> 6] = part;
    __syncthreads();
    if (tid == 0) b3t[o] = b3[o] + red[0] + red[1] + red[2] + red[3];
}

// bnfold4 (BN3 finalize inline from raw stats3): grid(16), block 128
__global__ void bnfold4_kernel(const float* __restrict__ w4, const float* __restrict__ b4,
                               const float* __restrict__ stats3,
                               const float* __restrict__ g3, const float* __restrict__ be3,
                               float* __restrict__ w4t, float* __restrict__ b4t) {
    const int o = blockIdx.x, tid = threadIdx.x;
    __shared__ float sc3s[32], sh3s[32];
    if (tid < 32) {
        const float n = (float)(B_ * L3_);
        const float m = stats3[tid] / n;
        const float v = stats3[32 + tid] / n - m * m;
        const float sc = rsqrtf(v + 1e-5f) * g3[tid];
        sc3s[tid] = sc;
        sh3s[tid] = be3[tid] - m * sc;
    }
    __syncthreads();
    float part = 0.f;
    if (tid < 96) {
        const int c = tid / 3;
        const float wv = w4[(size_t)o * 96 + tid];
        w4t[(size_t)tid * 16 + o] = wv * sc3s[c];
        part = wv * sh3s[c];
    }
#pragma unroll
    for (int off = 32; off > 0; off >>= 1) part += __shfl_down(part, off);
    __shared__ float red[2];
    if ((tid & 63) == 0) red[tid >> 6] = part;
    __syncthreads();
    if (tid == 0) b4t[o] = b4[o] + red[0] + red[1];
}

// ---------------------------------------------------------------------------
// conv2 (BN1 folded) + fused BN2 partial stats. 32 output channels/thread
// (4 o-blocks instead of 8): halves the re-reads of the 51 MB wave tensor.
// grid(32 b, 3 t, 4 o), block 256.
__global__ __launch_bounds__(256) void conv2_kernel(
        const float* __restrict__ in, const float* __restrict__ wt,
        const float* __restrict__ bt, float* __restrict__ out,
        float* __restrict__ stats2) {
    const int b  = blockIdx.x;
    const int tid = threadIdx.x;
    const int t  = blockIdx.y * 256 + tid;
    const int o0 = blockIdx.z * 32;
    float rv[32], qv[32];
#pragma unroll
    for (int j = 0; j < 32; ++j) rv[j] = 0.f;
    if (t < L2_) {
        v2f acc[16];
        const v2f* bt2 = (const v2f*)(bt + o0);
#pragma unroll
        for (int j = 0; j < 16; ++j) acc[j] = bt2[j];
        const float* inb = in + (size_t)b * WCH * T_ + t;
        for (int c = 0; c < WCH; ++c) {
            const float x0 = inb[c * T_], x1 = inb[c * T_ + 1], x2 = inb[c * T_ + 2];
            const v2f vx0 = {x0, x0}, vx1 = {x1, x1}, vx2 = {x2, x2};
            const v2f* wc = (const v2f*)(wt + (size_t)c * 384 + o0);  // k-stride 64 v2f
#pragma unroll
            for (int j = 0; j < 16; ++j)
                acc[j] = __builtin_elementwise_fma(wc[j], vx0,
                         __builtin_elementwise_fma(wc[64 + j], vx1,
                         __builtin_elementwise_fma(wc[128 + j], vx2, acc[j])));
        }
        const size_t ob = ((size_t)b * 128 + o0) * L2_ + t;
#pragma unroll
        for (int j = 0; j < 16; ++j) {
            rv[2 * j]     = fmaxf(acc[j].x, 0.f);
            rv[2 * j + 1] = fmaxf(acc[j].y, 0.f);
            out[ob + (size_t)(2 * j) * L2_]     = rv[2 * j];
            out[ob + (size_t)(2 * j + 1) * L2_] = rv[2 * j + 1];
        }
    }
#pragma unroll
    for (int j = 0; j < 32; ++j) qv[j] = rv[j] * rv[j];
#pragma unroll
    for (int off = 32; off > 0; off >>= 1) {
#pragma unroll
        for (int j = 0; j < 32; ++j) {
            rv[j] += __shfl_down(rv[j], off);
            qv[j] += __shfl_down(qv[j], off);
        }
    }
    __shared__ float red2[4][64];
    if ((tid & 63) == 0) {
        const int wv = tid >> 6;
#pragma unroll
        for (int j = 0; j < 32; ++j) { red2[wv][j] = rv[j]; red2[wv][32 + j] = qv[j]; }
    }
    __syncthreads();
    if (tid < 64) {
        const float a = red2[0][tid] + red2[1][tid] + red2[2][tid] + red2[3][tid];
        atomicAdd(&stats2[(tid >= 32 ? 128 : 0) + o0 + (tid & 31)], a);
    }
}

// conv3 (BN2 folded) + fused BN3 partial stats: grid(32 b, 2 t, 4 o), block 256
__global__ __launch_bounds__(256) void conv3_kernel(
        const float* __restrict__ in, const float* __restrict__ wt,
        const float* __restrict__ bt, float* __restrict__ out,
        float* __restrict__ stats3) {
    const int b  = blockIdx.x;
    const int tid = threadIdx.x;
    const int t  = blockIdx.y * 256 + tid;   // < 512 always
    const int o0 = blockIdx.z * 8;
    v2f acc[4];
    const v2f* bt2 = (const v2f*)(bt + o0);
#pragma unroll
    for (int j = 0; j < 4; ++j) acc[j] = bt2[j];
    const float* inb = in + (size_t)b * 128 * L2_ + t;
    for (int c = 0; c < 128; ++c) {
        const float x0 = inb[c * L2_], x1 = inb[c * L2_ + 1], x2 = inb[c * L2_ + 2];
        const float x3 = inb[c * L2_ + 3], x4 = inb[c * L2_ + 4];
        const v2f vx0 = {x0, x0}, vx1 = {x1, x1}, vx2 = {x2, x2}, vx3 = {x3, x3}, vx4 = {x4, x4};
        const v2f* wc = (const v2f*)(wt + (size_t)c * 160 + o0);  // k-stride 16 v2f
#pragma unroll
        for (int j = 0; j < 4; ++j)
            acc[j] = __builtin_elementwise_fma(wc[j], vx0,
                     __builtin_elementwise_fma(wc[16 + j], vx1,
                     __builtin_elementwise_fma(wc[32 + j], vx2,
                     __builtin_elementwise_fma(wc[48 + j], vx3,
                     __builtin_elementwise_fma(wc[64 + j], vx4, acc[j])))));
    }
    const size_t ob = ((size_t)b * 32 + o0) * L3_ + t;
    float rv[8], qv[8];
#pragma unroll
    for (int j = 0; j < 4; ++j) {
        rv[2 * j]     = fmaxf(acc[j].x, 0.f);
        rv[2 * j + 1] = fmaxf(acc[j].y, 0.f);
        out[ob + (size_t)(2 * j) * L3_]     = rv[2 * j];
        out[ob + (size_t)(2 * j + 1) * L3_] = rv[2 * j + 1];
    }
#pragma unroll
    for (int j = 0; j < 8; ++j) qv[j] = rv[j] * rv[j];
#pragma unroll
    for (int off = 32; off > 0; off >>= 1) {
#pragma unroll
        for (int j = 0; j < 8; ++j) {
            rv[j] += __shfl_down(rv[j], off);
            qv[j] += __shfl_down(qv[j], off);
        }
    }
    __shared__ float red3[4][16];
    if ((tid & 63) == 0) {
        const int wv = tid >> 6;
#pragma unroll
        for (int j = 0; j < 8; ++j) { red3[wv][j] = rv[j]; red3[wv][8 + j] = qv[j]; }
    }
    __syncthreads();
    if (tid < 16) {
        const float a = red3[0][tid] + red3[1][tid] + red3[2][tid] + red3[3][tid];
        atomicAdd(&stats3[(tid >= 8 ? 32 : 0) + o0 + (tid & 7)], a);
    }
}

// ---------------------------------------------------------------------------
// Fused conv4 + BN3-affine DWT + conv5 + per-(b,ch) stats. y4/y5 never
// materialized. grid(32), block 512.
__global__ __launch_bounds__(512) void tail_fused_kernel(
        const float* __restrict__ y3, const float* __restrict__ w4t,
        const float* __restrict__ b4t, const float* __restrict__ w5,
        const float* __restrict__ b5, const float* __restrict__ stats3,
        const float* __restrict__ g3, const float* __restrict__ be3,
        float* __restrict__ part) {
    const int b = blockIdx.x, l = threadIdx.x;  // l in [0,512)
    __shared__ float cm[L3_];
    __shared__ float bands[5][L3_];
    __shared__ float w5s[240];
    __shared__ float b5s[16], b4s[16];
    __shared__ float sc3s[32], sh3s[32];
    __shared__ float redf[8][64];
    if (l < 240) w5s[l] = w5[l];
    if (l < 16) { b5s[l] = b5[l]; b4s[l] = b4t[l]; }
    if (l >= 256 && l < 288) {
        const int ch = l - 256;
        const float n = (float)(B_ * L3_);
        const float m = stats3[ch] / n;
        const float v = stats3[32 + ch] / n - m * m;
        const float sc = rsqrtf(v + 1e-5f) * g3[ch];
        sc3s[ch] = sc;
        sh3s[ch] = be3[ch] - m * sc;
    }
    __syncthreads();
    v2f a4[8];
    const v2f* b4s2 = (const v2f*)b4s;
#pragma unroll
    for (int j = 0; j < 8; ++j) a4[j] = (v2f){0.f, 0.f};
    const float* yb = y3 + (size_t)b * 32 * L3_ + l;
    if (l < L4_) {
#pragma unroll
        for (int j = 0; j < 8; ++j) a4[j] = b4s2[j];
        for (int c = 0; c < 32; ++c) {
            const float x0 = yb[c * L3_], x1 = yb[c * L3_ + 1], x2 = yb[c * L3_ + 2];
            const v2f vx0 = {x0, x0}, vx1 = {x1, x1}, vx2 = {x2, x2};
            const v2f* wc = (const v2f*)(w4t + (size_t)c * 48);   // k-stride 8 v2f
#pragma unroll
            for (int j = 0; j < 8; ++j)
                a4[j] = __builtin_elementwise_fma(wc[j], vx0,
                        __builtin_elementwise_fma(wc[8 + j], vx1,
                        __builtin_elementwise_fma(wc[16 + j], vx2, a4[j])));
        }
    }
    {
        float s = 0.f, shs = 0.f;
        for (int ch = 0; ch < 32; ++ch) {
            s = fmaf(yb[ch * L3_], sc3s[ch], s);
            shs += sh3s[ch];
        }
        cm[l] = (s + shs) * (1.f / 32.f);
    }
    __syncthreads();
    const float s1 = 0.70710678118654752440f;
    const float s2c = 0.5f;
    const float s3 = 0.35355339059327378f;
    const float s4 = 0.25f;
    const int b16 = l & ~15, b8 = l & ~7, b4v = l & ~3, b2v = l & ~1;
    float sa = 0.f, sb = 0.f;
#pragma unroll
    for (int i = 0; i < 8; ++i) { sa += cm[b16 + i]; sb += cm[b16 + 8 + i]; }
    bands[0][l] = (sa + sb) * s4;
    bands[1][l] = (sa - sb) * s4;
    float ta = 0.f, tb = 0.f;
#pragma unroll
    for (int i = 0; i < 4; ++i) { ta += cm[b8 + i]; tb += cm[b8 + 4 + i]; }
    bands[2][l] = (ta - tb) * s3;
    bands[3][l] = (cm[b4v] + cm[b4v + 1] - cm[b4v + 2] - cm[b4v + 3]) * s2c;
    bands[4][l] = (cm[b2v] - cm[b2v + 1]) * s1;
    __syncthreads();
    float s4v[16], q4v[16], s5v[16], q5v[16];
#pragma unroll
    for (int o = 0; o < 16; ++o) { s5v[o] = 0.f; }
    if (l < L4_) {
        float in3[5][3];
#pragma unroll
        for (int c = 0; c < 5; ++c) {
            in3[c][0] = bands[c][l]; in3[c][1] = bands[c][l + 1]; in3[c][2] = bands[c][l + 2];
        }
#pragma unroll
        for (int o = 0; o < 16; ++o) {
            float acc = b5s[o];
#pragma unroll
            for (int c = 0; c < 5; ++c) {
                const float* wp = &w5s[(o * 5 + c) * 3];
                acc += in3[c][0] * wp[0] + in3[c][1] * wp[1] + in3[c][2] * wp[2];
            }
            s5v[o] = fmaxf(acc, 0.f);
        }
    }
#pragma unroll
    for (int j = 0; j < 8; ++j) {
        const float v0 = (l < L4_) ? fmaxf(a4[j].x, 0.f) : 0.f;
        const float v1 = (l < L4_) ? fmaxf(a4[j].y, 0.f) : 0.f;
        s4v[2 * j] = v0; s4v[2 * j + 1] = v1;
        q4v[2 * j] = v0 * v0; q4v[2 * j + 1] = v1 * v1;
    }
#pragma unroll
    for (int o = 0; o < 16; ++o) q5v[o] = s5v[o] * s5v[o];
#pragma unroll
    for (int off = 32; off > 0; off >>= 1) {
#pragma unroll
        for (int o = 0; o < 16; ++o) {
            s4v[o] += __shfl_down(s4v[o], off);
            q4v[o] += __shfl_down(q4v[o], off);
            s5v[o] += __shfl_down(s5v[o], off);
            q5v[o] += __shfl_down(q5v[o], off);
        }
    }
    if ((l & 63) == 0) {
        const int wv = l >> 6;
#pragma unroll
        for (int o = 0; o < 16; ++o) {
            redf[wv][o]      = s4v[o];
            redf[wv][16 + o] = q4v[o];
            redf[wv][32 + o] = s5v[o];
            redf[wv][48 + o] = q5v[o];
        }
    }
    __syncthreads();
    if (l < 64) {
        float a = 0.f;
#pragma unroll
        for (int wv = 0; wv < 8; ++wv) a += redf[wv][l];
        part[(size_t)(b * 16 + (l & 15)) * 4 + (l >> 4)] = a;
    }
}

// Tail stage B: BN4/BN5 stats + pooling(+affine) + FC. grid(1), block 512.
__global__ __launch_bounds__(512) void tail_final_kernel(
        const float* __restrict__ part,
        const float* __restrict__ g4, const float* __restrict__ be4,
        const float* __restrict__ g5, const float* __restrict__ be5,
        const float* __restrict__ fcw, const float* __restrict__ fcb,
        float* __restrict__ out) {
    const int p = threadIdx.x;           // 0..511
    const int b = p >> 4, ch = p & 15;
    const float4 v = ((const float4*)part)[b * 16 + ch];  // s4,q4,s5,q5
    __shared__ float S4[512], Q4[512], S5[512], Q5[512];
    __shared__ float M4[16], R4[16], M5[16], R5[16];
    __shared__ float pool[B_][16];
    S4[p] = v.x; Q4[p] = v.y; S5[p] = v.z; Q5[p] = v.w;
    __syncthreads();
    if (p < 16) {
        float ts = 0.f, tq = 0.f, us = 0.f, uq = 0.f;
        for (int bb = 0; bb < B_; ++bb) {
            ts += S4[bb * 16 + p]; tq += Q4[bb * 16 + p];
            us += S5[bb * 16 + p]; uq += Q5[bb * 16 + p];
        }
        const float n = (float)(B_ * L4_);
        float m = ts / n; M4[p] = m; R4[p] = rsqrtf(tq / n - m * m + 1e-5f);
        m = us / n;       M5[p] = m; R5[p] = rsqrtf(uq / n - m * m + 1e-5f);
    }
    __syncthreads();
    {
        const float mm4 = v.x / (float)L4_, mm5 = v.z / (float)L4_;
        const float v4 = (mm4 - M4[ch]) * R4[ch] * g4[ch] + be4[ch];
        const float v5 = (mm5 - M5[ch]) * R5[ch] * g5[ch] + be5[ch];
        pool[b][ch] = 0.5f * (v4 + v5);
    }
    __syncthreads();
    if (p < B_ * 10) {
        const int bb = p / 10, row = p - bb * 10;
        float a = fcb[row];
#pragma unroll
        for (int c = 0; c < 16; ++c) a += pool[bb][c] * fcw[row * 16 + c];
        out[bb * 10 + row] = a;
    }
}

// ---------------------------------------------------------------------------
extern "C" void kernel_launch(void* const* d_in, const int* in_sizes, int n_in,
                              void* d_out, int out_size, void* d_ws, size_t ws_size,
                              hipStream_t stream) {
    (void)in_sizes; (void)n_in; (void)out_size; (void)ws_size;
    const float* x   = (const float*)d_in[0];
    const float* wif = (const float*)d_in[1];
    const float* whf = (const float*)d_in[2];
    const float* bf  = (const float*)d_in[3];
    const float* wir = (const float*)d_in[4];
    const float* whr = (const float*)d_in[5];
    const float* br  = (const float*)d_in[6];
    const float* bw  = (const float*)d_in[7];
    const float* bb  = (const float*)d_in[8];
    const float* g1  = (const float*)d_in[9];  const float* be1 = (const float*)d_in[10];
    const float* g2  = (const float*)d_in[11]; const float* be2 = (const float*)d_in[12];
    const float* g3  = (const float*)d_in[13]; const float* be3 = (const float*)d_in[14];
    const float* g4  = (const float*)d_in[15]; const float* be4 = (const float*)d_in[16];
    const float* g5  = (const float*)d_in[17]; const float* be5 = (const float*)d_in[18];
    const float* w2  = (const float*)d_in[19]; const float* b2  = (const float*)d_in[20];
    const float* w3  = (const float*)d_in[21]; const float* b3  = (const float*)d_in[22];
    const float* w4  = (const float*)d_in[23]; const float* b4  = (const float*)d_in[24];
    const float* w5  = (const float*)d_in[25]; const float* b5  = (const float*)d_in[26];
    const float* fcw = (const float*)d_in[27]; const float* fcb = (const float*)d_in[28];
    float* out = (float*)d_out;
    float* ws  = (float*)d_ws;

    // Workspace layout (floats). xg region is reused by `wave` after the LSTM.
    float* xg_f  = ws;                       //  4,243,456
    float* xg_r  = ws + 4243456;             //  4,243,456
    float* wave  = ws;                       // 12,730,368 (reuses xg region)
    float* X     = ws + 12730368;            //  2,121,728 (dead after wave_kernel)
    float* y2    = ws + 14852096;            //  2,113,536
    float* y3    = ws + 16965632;            //    524,288
    float* stats = ws + 18012160;            //      1,536 (BN1 s/s2)
    float* m1 = ws + 18013696; float* r1 = m1 + 768;
    float* tpart  = r1 + 768;                //      2,048 (tail partials)
    float* stats2 = tpart + 2048;            //        256 (BN2 raw s/s2)
    float* stats3 = stats2 + 256;            //         64 (BN3 raw s/s2)
    // Folded weights live in the dead X region (X only read by wave_kernel):
    float* w2t  = X;                  // 294,912
    float* b2t  = X + 294912;         //     128
    float* w3t  = X + 295040;         //  20,480
    float* b3t  = X + 315520;         //      32
    float* w4t  = X + 315552;         //   1,536
    float* b4t  = X + 317088;         //      16
    // fp16 Whh lives in the y2 region (written by packw, read by lstm, then
    // y2 is overwritten by conv2 long after lstm completes):
    h2* w16f = (h2*)y2;               //  8,192 u32
    h2* w16r = (h2*)(y2 + 8192);      //  8,192 u32

    // 0) pack Whh to fp16 pairs
    packw_kernel<<<dim3(1), 256, 0, stream>>>(whf, whr, w16f, w16r);
    // 1) input projections (dir-split) + zero BN1/BN2/BN3 stats
    xg_kernel<<<dim3(65, 32, 2), 256, 0, stream>>>(x, wif, bf, wir, br, xg_f, xg_r,
                                                   stats, stats2);
    // 2) bidirectional LSTM recurrence -> X (unit-split, shfl gate exchange)
    lstm_kernel<<<dim3(64), 128, 0, stream>>>(xg_f, xg_r, w16f, w16r, X);
    // 3) wave module -> wave (raw), fused BN1 partial stats
    wave_kernel<<<dim3(3, CCH, B_), 256, 0, stream>>>(X, bw, bb, wave, stats);
    bn1_finalize_kernel<<<dim3(1), 768, 0, stream>>>(stats, m1, r1);
    // 4) fold BN1 into conv2 weights; conv2 on raw wave (+BN2 stats)
    bnfold2_kernel<<<dim3(128), 256, 0, stream>>>(w2, b2, m1, r1, g1, be1, w2t, b2t);
    conv2_kernel<<<dim3(32, 3, 4), 256, 0, stream>>>(wave, w2t, b2t, y2, stats2);
    // 5) fold BN2 (inline finalize) into conv3; conv3 (+BN3 stats)
    bnfold3_kernel<<<dim3(32), 256, 0, stream>>>(w3, b3, stats2, g2, be2, w3t, b3t);
    conv3_kernel<<<dim3(32, 2, 4), 256, 0, stream>>>(y2, w3t, b3t, y3, stats3);
    // 6) fold BN3 (inline finalize) into conv4 weights
    bnfold4_kernel<<<dim3(16), 128, 0, stream>>>(w4, b4, stats3, g3, be3, w4t, b4t);
    // 7) fused conv4 + DWT + conv5 + per-(b,ch) stats (no y4/y5 materialization)
    tail_fused_kernel<<<dim3(B_), 512, 0, stream>>>(y3, w4t, b4t, w5, b5,
                                                    stats3, g3, be3, tpart);
    // 8) BN4/BN5 stats + pooling + FC
    tail_final_kernel<<<dim3(1), 512, 0, stream>>>(tpart, g4, be4, g5, be5, fcw, fcb, out);
}

// Round 12
// 869.350 us; speedup vs baseline: 1.2092x; 1.2092x over previous
//
#include <hip/hip_runtime.h>
#include <math.h>

// Problem constants
#define B_     32
#define F_     64
#define T_     518
#define HID    64
#define GATES  256   // 4*HID
#define CCH    128   // 2*HID lstm output channels
#define NWAVE  6
#define WCH    768   // NWAVE*CCH
#define L2_    516   // T-2   (conv2 out)
#define L3_    512   // L2-4  (conv3 out)
#define L4_    510   // L3-2  (conv4/conv5 out)

typedef float v2f __attribute__((ext_vector_type(2)));
typedef _Float16 h2 __attribute__((ext_vector_type(2)));

__device__ __forceinline__ float frcp(float x) { return __builtin_amdgcn_rcpf(x); }
__device__ __forceinline__ float fsigmoid(float x) { return frcp(1.f + __expf(-x)); }
__device__ __forceinline__ float ftanh(float x) { return 1.f - 2.f * frcp(1.f + __expf(2.f * x)); }

__device__ __forceinline__ float fdot2(h2 a, h2 b, float c) {
#if __has_builtin(__builtin_amdgcn_fdot2)
    return __builtin_amdgcn_fdot2(a, b, c, false);
#else
    return fmaf((float)a[0], (float)b[0], fmaf((float)a[1], (float)b[1], c));
#endif
}

// ---------------------------------------------------------------------------
// K0: pack Whh (both dirs) to fp16 pairs. 1 block, 256 threads.
__global__ void packw_kernel(const float* __restrict__ whf, const float* __restrict__ whr,
                             h2* __restrict__ w16f, h2* __restrict__ w16r) {
    const int row = threadIdx.x;
    const float* sf = whf + (size_t)row * HID;
    const float* sr = whr + (size_t)row * HID;
#pragma unroll
    for (int i = 0; i < 32; ++i) {
        w16f[row * 32 + i] = (h2){(_Float16)sf[2 * i], (_Float16)sf[2 * i + 1]};
        w16r[row * 32 + i] = (h2){(_Float16)sr[2 * i], (_Float16)sr[2 * i + 1]};
    }
}

// ---------------------------------------------------------------------------
// K1: input projections, dir-split (grid z = dir) so each thread holds only
// 16 float4 of weights (64 VGPRs < remat threshold). Layout xg[t][p][u][g2].
__global__ void xg_kernel(const float* __restrict__ x,
                          const float* __restrict__ wif, const float* __restrict__ bf,
                          const float* __restrict__ wir, const float* __restrict__ br,
                          float* __restrict__ xg_f, float* __restrict__ xg_r,
                          float* __restrict__ stats, float* __restrict__ stats23) {
    if (blockIdx.x == 0 && blockIdx.y == 0 && blockIdx.z == 0) {
        for (int i = threadIdx.x; i < 2 * WCH; i += 256) stats[i] = 0.f;
        if (threadIdx.x < 320) stats23[threadIdx.x] = 0.f;   // 256 BN2 + 64 BN3
    }
    const int dir = blockIdx.z;
    const float* wi = dir ? wir : wif;
    const float* bi = dir ? br : bf;
    float* xgo = dir ? xg_r : xg_f;
    const int tid = threadIdx.x;
    const int wv  = tid >> 7;
    const int g2  = tid & 1;
    const int r   = (tid >> 1) & 63;
    const int g   = (2 * wv + g2) * 64 + r;       // gate row; store offset == tid
    const int b   = blockIdx.y;
    const int t0  = blockIdx.x * 8;
    float4 wa[16];
    const float4* w0 = (const float4*)(wi + g * F_);
#pragma unroll
    for (int i = 0; i < 16; ++i) wa[i] = w0[i];
    const float bv = bi[g];
    for (int tt = 0; tt < 8; ++tt) {
        const int t = t0 + tt;
        if (t >= T_) break;
        const float* xp = x + (size_t)b * F_ * T_ + t;
        float a0 = bv;
#pragma unroll
        for (int i = 0; i < 16; ++i) {
            float x0 = xp[(i * 4 + 0) * T_];
            float x1 = xp[(i * 4 + 1) * T_];
            float x2 = xp[(i * 4 + 2) * T_];
            float x3 = xp[(i * 4 + 3) * T_];
            a0 += wa[i].x * x0 + wa[i].y * x1 + wa[i].z * x2 + wa[i].w * x3;
        }
        xgo[((size_t)b * T_ + t) * GATES + tid] = a0;   // coalesced
    }
}

// ---------------------------------------------------------------------------
// K2: LSTM recurrence — UNIT-SPLIT 2-wave structure (R11-proven: shfl gate
// exchange instead of LDS round-trip broke the serial-chain floor).
// grid(64), block 128.
__global__ __launch_bounds__(128, 1) void lstm_kernel(
        const float* __restrict__ xgi_f, const float* __restrict__ xgi_r,
        const h2* __restrict__ w16f, const h2* __restrict__ w16r,
        float* __restrict__ X) {
    const int dir = blockIdx.x & 1;
    const int b   = blockIdx.x >> 1;
    const float* xg  = (dir ? xgi_r : xgi_f) + (size_t)b * T_ * GATES;
    const h2* w16 = dir ? w16r : w16f;
    const int tid = threadIdx.x;
    const int lw  = tid & 63;            // lane in wave
    const int w   = tid >> 6;            // wave id
    const int p   = lw >> 5;             // gate-pair: 0 -> (i,f), 1 -> (g,o)
    const int u   = 32 * w + (lw & 31);  // unit owned

    union U4 { uint4 u4; h2 h[4]; };
    U4 wA[8], wB[8];                     // rows (2p)*64+u and (2p+1)*64+u
    {
        const uint4* pA = (const uint4*)(w16 + (size_t)((2 * p) * HID + u) * 32);
        const uint4* pB = (const uint4*)(w16 + (size_t)((2 * p + 1) * HID + u) * 32);
#pragma unroll
        for (int i = 0; i < 8; ++i) { wA[i].u4 = pA[i]; wB[i].u4 = pB[i]; }
    }

    __shared__ __align__(16) _Float16 hs16[2][HID];   // double-buffered h
    if (lw < 32) { hs16[0][u] = (_Float16)0.f; hs16[1][u] = (_Float16)0.f; }
    float c = 0.f;
    float* Xrow = X + ((size_t)(b * CCH + dir * HID + u)) * T_;

    int t = dir ? (T_ - 1) : 0;
    const int step = dir ? -1 : 1;
    const float2* xg2 = (const float2*)xg;   // index (t*2 + p)*64 + u
    float2 q0 = xg2[((size_t)t * 2 + p) * 64 + u];
    float2 q1 = xg2[((size_t)(t + step) * 2 + p) * 64 + u];
    __syncthreads();

    for (int s = 0; s < T_; ++s) {
        const uint4* hp4 = (const uint4*)hs16[(s + 1) & 1];   // prev step's h
        float a0 = q0.x, a0b = 0.f;
        float a1 = q0.y, a1b = 0.f;
#pragma unroll
        for (int i = 0; i < 8; ++i) {
            U4 hv; hv.u4 = hp4[i];
            a0  = fdot2(wA[i].h[0], hv.h[0], a0);
            a0b = fdot2(wA[i].h[1], hv.h[1], a0b);
            a0  = fdot2(wA[i].h[2], hv.h[2], a0);
            a0b = fdot2(wA[i].h[3], hv.h[3], a0b);
            a1  = fdot2(wB[i].h[0], hv.h[0], a1);
            a1b = fdot2(wB[i].h[1], hv.h[1], a1b);
            a1  = fdot2(wB[i].h[2], hv.h[2], a1);
            a1b = fdot2(wB[i].h[3], hv.h[3], a1b);
        }
        const float gA = a0 + a0b;    // gate (2p)*64+u
        const float gB = a1 + a1b;    // gate (2p+1)*64+u
        const float oA = __shfl_xor(gA, 32, 64);
        const float oB = __shfl_xor(gB, 32, 64);
        const float gi = p ? oA : gA;
        const float gf = p ? oB : gB;
        const float gg = p ? gA : oA;
        const float go = p ? gB : oB;

        // prefetch next xg before the dependent tail
        int tp = t + 2 * step;
        tp = tp < 0 ? 0 : (tp >= T_ ? T_ - 1 : tp);
        const float2 qn = xg2[((size_t)tp * 2 + p) * 64 + u];

        const float si = fsigmoid(gi);
        const float sf = fsigmoid(gf);
        const float so = fsigmoid(go);
        c = sf * c + si * ftanh(gg);
        const float h = so * ftanh(c);

        if (lw < 32) { hs16[s & 1][u] = (_Float16)h; Xrow[t] = h; }
        asm volatile("s_waitcnt lgkmcnt(0)" ::: "memory");
        __builtin_amdgcn_s_barrier();

        q0 = q1; q1 = qn;
        t += step;
    }
}

// ---------------------------------------------------------------------------
// K3: wave module + fused BN1 partial stats. Chebyshev cos recurrence.
// grid(3, 128, 32), block 256
__global__ void wave_kernel(const float* __restrict__ X,
                            const float* __restrict__ bw, const float* __restrict__ bb,
                            float* __restrict__ wave, float* __restrict__ stats) {
    const int b = blockIdx.z, c = blockIdx.y;
    const int t0 = blockIdx.x * 256;
    const int tid = threadIdx.x;
    __shared__ float xs[256 + 14];
    __shared__ float bws[NWAVE][16];
    __shared__ float bbs[NWAVE];
    __shared__ float red[4][12];
    const float* xrow = X + ((size_t)(b * CCH + c)) * T_;
    for (int i = tid; i < 270; i += 256) {
        int tt = t0 - 7 + i;
        xs[i] = (tt >= 0 && tt < T_) ? xrow[tt] : 0.f;
    }
    if (tid < NWAVE * 15) bws[tid / 15][tid % 15] = bw[tid];
    if (tid < NWAVE) bbs[tid] = bb[tid];
    __syncthreads();
    const int t = t0 + tid;
    float ls[NWAVE], lq[NWAVE];
#pragma unroll
    for (int ii = 0; ii < NWAVE; ++ii) { ls[ii] = 0.f; lq[ii] = 0.f; }
    if (t < T_) {
        float win[15];
#pragma unroll
        for (int k = 0; k < 15; ++k) win[k] = xs[tid + k];
        float e[8];
        e[0] = win[7];
#pragma unroll
        for (int m = 1; m < 8; ++m) e[m] = win[7 - m] + win[7 + m];
        const float c0 = 6.28318530717958647692f / 15.f;  // 2*pi/WIDE
#pragma unroll
        for (int ii = 0; ii < NWAVE; ++ii) {
            float sc = bbs[ii];
#pragma unroll
            for (int k = 0; k < 15; ++k) sc += win[k] * bws[ii][k];
            sc = fmaxf(sc, 0.f);
            const float phi = c0 * (float)(ii + 1) * sc;
            const float c1 = __cosf(phi);
            float o = fmaf(e[1], c1, e[0]);
            float cp = 1.f, cc = c1;
#pragma unroll
            for (int m = 2; m < 8; ++m) {
                const float cn = fmaf(2.f * c1, cc, -cp);   // cos(m*phi)
                o = fmaf(e[m], cn, o);
                cp = cc; cc = cn;
            }
            const float q = (truncf(sc * 15.f) + 1.f) * (2.f / 17.f);
            const float val = o * rsqrtf(q);
            wave[((size_t)(b * WCH + ii * CCH + c)) * T_ + t] = val;
            ls[ii] = val;
            lq[ii] = val * val;
        }
    }
#pragma unroll
    for (int off = 32; off > 0; off >>= 1) {
#pragma unroll
        for (int ii = 0; ii < NWAVE; ++ii) {
            ls[ii] += __shfl_down(ls[ii], off);
            lq[ii] += __shfl_down(lq[ii], off);
        }
    }
    if ((tid & 63) == 0) {
        const int w = tid >> 6;
#pragma unroll
        for (int ii = 0; ii < NWAVE; ++ii) { red[w][ii] = ls[ii]; red[w][6 + ii] = lq[ii]; }
    }
    __syncthreads();
    if (tid < 12) {
        const float a = red[0][tid] + red[1][tid] + red[2][tid] + red[3][tid];
        const int ii = tid % 6;
        const int ch = ii * CCH + c;
        atomicAdd(&stats[(tid >= 6 ? WCH : 0) + ch], a);
    }
}

// Finalize BN1 stats: 1 block, 768 threads
__global__ void bn1_finalize_kernel(const float* __restrict__ stats,
                                    float* __restrict__ mean, float* __restrict__ rstd) {
    const int c = threadIdx.x;
    const float n = (float)(B_ * T_);
    const float m = stats[c] / n;
    const float v = stats[WCH + c] / n - m * m;
    mean[c] = m;
    rstd[c] = rsqrtf(v + 1e-5f);
}

// ---------------------------------------------------------------------------
// bnfold2: grid(128), block 256 (one block per output channel)
__global__ void bnfold2_kernel(const float* __restrict__ w2, const float* __restrict__ b2,
                               const float* __restrict__ m1, const float* __restrict__ r1,
                               const float* __restrict__ g1, const float* __restrict__ be1,
                               float* __restrict__ w2t, float* __restrict__ b2t) {
    const int o = blockIdx.x, tid = threadIdx.x;
    float part = 0.f;
    for (int idx = tid; idx < WCH * 3; idx += 256) {
        const int c = idx / 3;
        const float sc = r1[c] * g1[c];
        const float sh = be1[c] - m1[c] * sc;
        const float wv = w2[(size_t)o * (WCH * 3) + idx];
        w2t[(size_t)idx * 128 + o] = wv * sc;
        part += wv * sh;
    }
#pragma unroll
    for (int off = 32; off > 0; off >>= 1) part += __shfl_down(part, off);
    __shared__ float red[4];
    if ((tid & 63) == 0) red[tid >> 6] = part;
    __syncthreads();
    if (tid == 0) b2t[o] = b2[o] + red[0] + red[1] + red[2] + red[3];
}

// bnfold3 (BN2 finalize inline from raw stats2): grid(32), block 256
__global__ void bnfold3_kernel(const float* __restrict__ w3, const float* __restrict__ b3,
                               const float* __restrict__ stats2,
                               const float* __restrict__ g2, const float* __restrict__ be2,
                               float* __restrict__ w3t, float* __restrict__ b3t) {
    const int o = blockIdx.x, tid = threadIdx.x;
    __shared__ float sc2s[128], sh2s[128];
    if (tid < 128) {
        const float n = (float)(B_ * L2_);
        const float m = stats2[tid] / n;
        const float v = stats2[128 + tid] / n - m * m;
        const float sc = rsqrtf(v + 1e-5f) * g2[tid];
        sc2s[tid] = sc;
        sh2s[tid] = be2[tid] - m * sc;
    }
    __syncthreads();
    float part = 0.f;
    for (int idx = tid; idx < 128 * 5; idx += 256) {
        const int c = idx / 5;
        const float wv = w3[(size_t)o * 640 + idx];
        w3t[(size_t)idx * 32 + o] = wv * sc2s[c];
        part += wv * sh2s[c];
    }
#pragma unroll
    for (int off = 32; off > 0; off >>= 1) part += __shfl_down(part, off);
    __shared__ float red[4];
    if ((tid & 63) == 0) red[tid >> 6] = part;
    __syncthreads();
    if (tid == 0) b3t[o] = b3[o] + red[0] + red[1] + red[2] + red[3];
}

// bnfold4 (BN3 finalize inline from raw stats3): grid(16), block 128
__global__ void bnfold4_kernel(const float* __restrict__ w4, const float* __restrict__ b4,
                               const float* __restrict__ stats3,
                               const float* __restrict__ g3, const float* __restrict__ be3,
                               float* __restrict__ w4t, float* __restrict__ b4t) {
    const int o = blockIdx.x, tid = threadIdx.x;
    __shared__ float sc3s[32], sh3s[32];
    if (tid < 32) {
        const float n = (float)(B_ * L3_);
        const float m = stats3[tid] / n;
        const float v = stats3[32 + tid] / n - m * m;
        const float sc = rsqrtf(v + 1e-5f) * g3[tid];
        sc3s[tid] = sc;
        sh3s[tid] = be3[tid] - m * sc;
    }
    __syncthreads();
    float part = 0.f;
    if (tid < 96) {
        const int c = tid / 3;
        const float wv = w4[(size_t)o * 96 + tid];
        w4t[(size_t)tid * 16 + o] = wv * sc3s[c];
        part = wv * sh3s[c];
    }
#pragma unroll
    for (int off = 32; off > 0; off >>= 1) part += __shfl_down(part, off);
    __shared__ float red[2];
    if ((tid & 63) == 0) red[tid >> 6] = part;
    __syncthreads();
    if (tid == 0) b4t[o] = b4[o] + red[0] + red[1];
}

// ---------------------------------------------------------------------------
// conv2 (BN1 folded) + fused BN2 partial stats: R9-proven 16-ch/thread
// variant (VGPR 36, no spill). grid(32 b, 3 t, 8 o), block 256.
__global__ __launch_bounds__(256) void conv2_kernel(
        const float* __restrict__ in, const float* __restrict__ wt,
        const float* __restrict__ bt, float* __restrict__ out,
        float* __restrict__ stats2) {
    const int b  = blockIdx.x;
    const int tid = threadIdx.x;
    const int t  = blockIdx.y * 256 + tid;
    const int o0 = blockIdx.z * 16;
    float rv[16], qv[16];
#pragma unroll
    for (int j = 0; j < 16; ++j) rv[j] = 0.f;
    if (t < L2_) {
        v2f acc[8];
        const v2f* bt2 = (const v2f*)(bt + o0);
#pragma unroll
        for (int j = 0; j < 8; ++j) acc[j] = bt2[j];
        const float* inb = in + (size_t)b * WCH * T_ + t;
        for (int c = 0; c < WCH; ++c) {
            const float x0 = inb[c * T_], x1 = inb[c * T_ + 1], x2 = inb[c * T_ + 2];
            const v2f vx0 = {x0, x0}, vx1 = {x1, x1}, vx2 = {x2, x2};
            const v2f* wc = (const v2f*)(wt + (size_t)c * 384 + o0);  // k-stride 64 v2f
#pragma unroll
            for (int j = 0; j < 8; ++j)
                acc[j] = __builtin_elementwise_fma(wc[j], vx0,
                         __builtin_elementwise_fma(wc[64 + j], vx1,
                         __builtin_elementwise_fma(wc[128 + j], vx2, acc[j])));
        }
        const size_t ob = ((size_t)b * 128 + o0) * L2_ + t;
#pragma unroll
        for (int j = 0; j < 8; ++j) {
            rv[2 * j]     = fmaxf(acc[j].x, 0.f);
            rv[2 * j + 1] = fmaxf(acc[j].y, 0.f);
            out[ob + (size_t)(2 * j) * L2_]     = rv[2 * j];
            out[ob + (size_t)(2 * j + 1) * L2_] = rv[2 * j + 1];
        }
    }
#pragma unroll
    for (int j = 0; j < 16; ++j) qv[j] = rv[j] * rv[j];
#pragma unroll
    for (int off = 32; off > 0; off >>= 1) {
#pragma unroll
        for (int j = 0; j < 16; ++j) {
            rv[j] += __shfl_down(rv[j], off);
            qv[j] += __shfl_down(qv[j], off);
        }
    }
    __shared__ float red2[4][32];
    if ((tid & 63) == 0) {
        const int wv = tid >> 6;
#pragma unroll
        for (int j = 0; j < 16; ++j) { red2[wv][j] = rv[j]; red2[wv][16 + j] = qv[j]; }
    }
    __syncthreads();
    if (tid < 32) {
        const float a = red2[0][tid] + red2[1][tid] + red2[2][tid] + red2[3][tid];
        atomicAdd(&stats2[(tid >= 16 ? 128 : 0) + o0 + (tid & 15)], a);
    }
}

// conv3 (BN2 folded) + fused BN3 partial stats: grid(32 b, 2 t, 4 o), block 256
__global__ __launch_bounds__(256) void conv3_kernel(
        const float* __restrict__ in, const float* __restrict__ wt,
        const float* __restrict__ bt, float* __restrict__ out,
        float* __restrict__ stats3) {
    const int b  = blockIdx.x;
    const int tid = threadIdx.x;
    const int t  = blockIdx.y * 256 + tid;   // < 512 always
    const int o0 = blockIdx.z * 8;
    v2f acc[4];
    const v2f* bt2 = (const v2f*)(bt + o0);
#pragma unroll
    for (int j = 0; j < 4; ++j) acc[j] = bt2[j];
    const float* inb = in + (size_t)b * 128 * L2_ + t;
    for (int c = 0; c < 128; ++c) {
        const float x0 = inb[c * L2_], x1 = inb[c * L2_ + 1], x2 = inb[c * L2_ + 2];
        const float x3 = inb[c * L2_ + 3], x4 = inb[c * L2_ + 4];
        const v2f vx0 = {x0, x0}, vx1 = {x1, x1}, vx2 = {x2, x2}, vx3 = {x3, x3}, vx4 = {x4, x4};
        const v2f* wc = (const v2f*)(wt + (size_t)c * 160 + o0);  // k-stride 16 v2f
#pragma unroll
        for (int j = 0; j < 4; ++j)
            acc[j] = __builtin_elementwise_fma(wc[j], vx0,
                     __builtin_elementwise_fma(wc[16 + j], vx1,
                     __builtin_elementwise_fma(wc[32 + j], vx2,
                     __builtin_elementwise_fma(wc[48 + j], vx3,
                     __builtin_elementwise_fma(wc[64 + j], vx4, acc[j])))));
    }
    const size_t ob = ((size_t)b * 32 + o0) * L3_ + t;
    float rv[8], qv[8];
#pragma unroll
    for (int j = 0; j < 4; ++j) {
        rv[2 * j]     = fmaxf(acc[j].x, 0.f);
        rv[2 * j + 1] = fmaxf(acc[j].y, 0.f);
        out[ob + (size_t)(2 * j) * L3_]     = rv[2 * j];
        out[ob + (size_t)(2 * j + 1) * L3_] = rv[2 * j + 1];
    }
#pragma unroll
    for (int j = 0; j < 8; ++j) qv[j] = rv[j] * rv[j];
#pragma unroll
    for (int off = 32; off > 0; off >>= 1) {
#pragma unroll
        for (int j = 0; j < 8; ++j) {
            rv[j] += __shfl_down(rv[j], off);
            qv[j] += __shfl_down(qv[j], off);
        }
    }
    __shared__ float red3[4][16];
    if ((tid & 63) == 0) {
        const int wv = tid >> 6;
#pragma unroll
        for (int j = 0; j < 8; ++j) { red3[wv][j] = rv[j]; red3[wv][8 + j] = qv[j]; }
    }
    __syncthreads();
    if (tid < 16) {
        const float a = red3[0][tid] + red3[1][tid] + red3[2][tid] + red3[3][tid];
        atomicAdd(&stats3[(tid >= 8 ? 32 : 0) + o0 + (tid & 7)], a);
    }
}

// ---------------------------------------------------------------------------
// Fused conv4 + BN3-affine DWT + conv5 + per-(b,ch) stats. y4/y5 never
// materialized. grid(32), block 512.
__global__ __launch_bounds__(512) void tail_fused_kernel(
        const float* __restrict__ y3, const float* __restrict__ w4t,
        const float* __restrict__ b4t, const float* __restrict__ w5,
        const float* __restrict__ b5, const float* __restrict__ stats3,
        const float* __restrict__ g3, const float* __restrict__ be3,
        float* __restrict__ part) {
    const int b = blockIdx.x, l = threadIdx.x;  // l in [0,512)
    __shared__ float cm[L3_];
    __shared__ float bands[5][L3_];
    __shared__ float w5s[240];
    __shared__ float b5s[16], b4s[16];
    __shared__ float sc3s[32], sh3s[32];
    __shared__ float redf[8][64];
    if (l < 240) w5s[l] = w5[l];
    if (l < 16) { b5s[l] = b5[l]; b4s[l] = b4t[l]; }
    if (l >= 256 && l < 288) {
        const int ch = l - 256;
        const float n = (float)(B_ * L3_);
        const float m = stats3[ch] / n;
        const float v = stats3[32 + ch] / n - m * m;
        const float sc = rsqrtf(v + 1e-5f) * g3[ch];
        sc3s[ch] = sc;
        sh3s[ch] = be3[ch] - m * sc;
    }
    __syncthreads();
    v2f a4[8];
    const v2f* b4s2 = (const v2f*)b4s;
#pragma unroll
    for (int j = 0; j < 8; ++j) a4[j] = (v2f){0.f, 0.f};
    const float* yb = y3 + (size_t)b * 32 * L3_ + l;
    if (l < L4_) {
#pragma unroll
        for (int j = 0; j < 8; ++j) a4[j] = b4s2[j];
        for (int c = 0; c < 32; ++c) {
            const float x0 = yb[c * L3_], x1 = yb[c * L3_ + 1], x2 = yb[c * L3_ + 2];
            const v2f vx0 = {x0, x0}, vx1 = {x1, x1}, vx2 = {x2, x2};
            const v2f* wc = (const v2f*)(w4t + (size_t)c * 48);   // k-stride 8 v2f
#pragma unroll
            for (int j = 0; j < 8; ++j)
                a4[j] = __builtin_elementwise_fma(wc[j], vx0,
                        __builtin_elementwise_fma(wc[8 + j], vx1,
                        __builtin_elementwise_fma(wc[16 + j], vx2, a4[j])));
        }
    }
    {
        float s = 0.f, shs = 0.f;
        for (int ch = 0; ch < 32; ++ch) {
            s = fmaf(yb[ch * L3_], sc3s[ch], s);
            shs += sh3s[ch];
        }
        cm[l] = (s + shs) * (1.f / 32.f);
    }
    __syncthreads();
    const float s1 = 0.70710678118654752440f;
    const float s2c = 0.5f;
    const float s3 = 0.35355339059327378f;
    const float s4 = 0.25f;
    const int b16 = l & ~15, b8 = l & ~7, b4v = l & ~3, b2v = l & ~1;
    float sa = 0.f, sb = 0.f;
#pragma unroll
    for (int i = 0; i < 8; ++i) { sa += cm[b16 + i]; sb += cm[b16 + 8 + i]; }
    bands[0][l] = (sa + sb) * s4;
    bands[1][l] = (sa - sb) * s4;
    float ta = 0.f, tb = 0.f;
#pragma unroll
    for (int i = 0; i < 4; ++i) { ta += cm[b8 + i]; tb += cm[b8 + 4 + i]; }
    bands[2][l] = (ta - tb) * s3;
    bands[3][l] = (cm[b4v] + cm[b4v + 1] - cm[b4v + 2] - cm[b4v + 3]) * s2c;
    bands[4][l] = (cm[b2v] - cm[b2v + 1]) * s1;
    __syncthreads();
    float s4v[16], q4v[16], s5v[16], q5v[16];
#pragma unroll
    for (int o = 0; o < 16; ++o) { s5v[o] = 0.f; }
    if (l < L4_) {
        float in3[5][3];
#pragma unroll
        for (int c = 0; c < 5; ++c) {
            in3[c][0] = bands[c][l]; in3[c][1] = bands[c][l + 1]; in3[c][2] = bands[c][l + 2];
        }
#pragma unroll
        for (int o = 0; o < 16; ++o) {
            float acc = b5s[o];
#pragma unroll
            for (int c = 0; c < 5; ++c) {
                const float* wp = &w5s[(o * 5 + c) * 3];
                acc += in3[c][0] * wp[0] + in3[c][1] * wp[1] + in3[c][2] * wp[2];
            }
            s5v[o] = fmaxf(acc, 0.f);
        }
    }
#pragma unroll
    for (int j = 0; j < 8; ++j) {
        const float v0 = (l < L4_) ? fmaxf(a4[j].x, 0.f) : 0.f;
        const float v1 = (l < L4_) ? fmaxf(a4[j].y, 0.f) : 0.f;
        s4v[2 * j] = v0; s4v[2 * j + 1] = v1;
        q4v[2 * j] = v0 * v0; q4v[2 * j + 1] = v1 * v1;
    }
#pragma unroll
    for (int o = 0; o < 16; ++o) q5v[o] = s5v[o] * s5v[o];
#pragma unroll
    for (int off = 32; off > 0; off >>= 1) {
#pragma unroll
        for (int o = 0; o < 16; ++o) {
            s4v[o] += __shfl_down(s4v[o], off);
            q4v[o] += __shfl_down(q4v[o], off);
            s5v[o] += __shfl_down(s5v[o], off);
            q5v[o] += __shfl_down(q5v[o], off);
        }
    }
    if ((l & 63) == 0) {
        const int wv = l >> 6;
#pragma unroll
        for (int o = 0; o < 16; ++o) {
            redf[wv][o]      = s4v[o];
            redf[wv][16 + o] = q4v[o];
            redf[wv][32 + o] = s5v[o];
            redf[wv][48 + o] = q5v[o];
        }
    }
    __syncthreads();
    if (l < 64) {
        float a = 0.f;
#pragma unroll
        for (int wv = 0; wv < 8; ++wv) a += redf[wv][l];
        part[(size_t)(b * 16 + (l & 15)) * 4 + (l >> 4)] = a;
    }
}

// Tail stage B: BN4/BN5 stats + pooling(+affine) + FC. grid(1), block 512.
__global__ __launch_bounds__(512) void tail_final_kernel(
        const float* __restrict__ part,
        const float* __restrict__ g4, const float* __restrict__ be4,
        const float* __restrict__ g5, const float* __restrict__ be5,
        const float* __restrict__ fcw, const float* __restrict__ fcb,
        float* __restrict__ out) {
    const int p = threadIdx.x;           // 0..511
    const int b = p >> 4, ch = p & 15;
    const float4 v = ((const float4*)part)[b * 16 + ch];  // s4,q4,s5,q5
    __shared__ float S4[512], Q4[512], S5[512], Q5[512];
    __shared__ float M4[16], R4[16], M5[16], R5[16];
    __shared__ float pool[B_][16];
    S4[p] = v.x; Q4[p] = v.y; S5[p] = v.z; Q5[p] = v.w;
    __syncthreads();
    if (p < 16) {
        float ts = 0.f, tq = 0.f, us = 0.f, uq = 0.f;
        for (int bb = 0; bb < B_; ++bb) {
            ts += S4[bb * 16 + p]; tq += Q4[bb * 16 + p];
            us += S5[bb * 16 + p]; uq += Q5[bb * 16 + p];
        }
        const float n = (float)(B_ * L4_);
        float m = ts / n; M4[p] = m; R4[p] = rsqrtf(tq / n - m * m + 1e-5f);
        m = us / n;       M5[p] = m; R5[p] = rsqrtf(uq / n - m * m + 1e-5f);
    }
    __syncthreads();
    {
        const float mm4 = v.x / (float)L4_, mm5 = v.z / (float)L4_;
        const float v4 = (mm4 - M4[ch]) * R4[ch] * g4[ch] + be4[ch];
        const float v5 = (mm5 - M5[ch]) * R5[ch] * g5[ch] + be5[ch];
        pool[b][ch] = 0.5f * (v4 + v5);
    }
    __syncthreads();
    if (p < B_ * 10) {
        const int bb = p / 10, row = p - bb * 10;
        float a = fcb[row];
#pragma unroll
        for (int c = 0; c < 16; ++c) a += pool[bb][c] * fcw[row * 16 + c];
        out[bb * 10 + row] = a;
    }
}

// ---------------------------------------------------------------------------
extern "C" void kernel_launch(void* const* d_in, const int* in_sizes, int n_in,
                              void* d_out, int out_size, void* d_ws, size_t ws_size,
                              hipStream_t stream) {
    (void)in_sizes; (void)n_in; (void)out_size; (void)ws_size;
    const float* x   = (const float*)d_in[0];
    const float* wif = (const float*)d_in[1];
    const float* whf = (const float*)d_in[2];
    const float* bf  = (const float*)d_in[3];
    const float* wir = (const float*)d_in[4];
    const float* whr = (const float*)d_in[5];
    const float* br  = (const float*)d_in[6];
    const float* bw  = (const float*)d_in[7];
    const float* bb  = (const float*)d_in[8];
    const float* g1  = (const float*)d_in[9];  const float* be1 = (const float*)d_in[10];
    const float* g2  = (const float*)d_in[11]; const float* be2 = (const float*)d_in[12];
    const float* g3  = (const float*)d_in[13]; const float* be3 = (const float*)d_in[14];
    const float* g4  = (const float*)d_in[15]; const float* be4 = (const float*)d_in[16];
    const float* g5  = (const float*)d_in[17]; const float* be5 = (const float*)d_in[18];
    const float* w2  = (const float*)d_in[19]; const float* b2  = (const float*)d_in[20];
    const float* w3  = (const float*)d_in[21]; const float* b3  = (const float*)d_in[22];
    const float* w4  = (const float*)d_in[23]; const float* b4  = (const float*)d_in[24];
    const float* w5  = (const float*)d_in[25]; const float* b5  = (const float*)d_in[26];
    const float* fcw = (const float*)d_in[27]; const float* fcb = (const float*)d_in[28];
    float* out = (float*)d_out;
    float* ws  = (float*)d_ws;

    // Workspace layout (floats). xg region is reused by `wave` after the LSTM.
    float* xg_f  = ws;                       //  4,243,456
    float* xg_r  = ws + 4243456;             //  4,243,456
    float* wave  = ws;                       // 12,730,368 (reuses xg region)
    float* X     = ws + 12730368;            //  2,121,728 (dead after wave_kernel)
    float* y2    = ws + 14852096;            //  2,113,536
    float* y3    = ws + 16965632;            //    524,288
    float* stats = ws + 18012160;            //      1,536 (BN1 s/s2)
    float* m1 = ws + 18013696; float* r1 = m1 + 768;
    float* tpart  = r1 + 768;                //      2,048 (tail partials)
    float* stats2 = tpart + 2048;            //        256 (BN2 raw s/s2)
    float* stats3 = stats2 + 256;            //         64 (BN3 raw s/s2)
    // Folded weights live in the dead X region (X only read by wave_kernel):
    float* w2t  = X;                  // 294,912
    float* b2t  = X + 294912;         //     128
    float* w3t  = X + 295040;         //  20,480
    float* b3t  = X + 315520;         //      32
    float* w4t  = X + 315552;         //   1,536
    float* b4t  = X + 317088;         //      16
    // fp16 Whh lives in the y2 region (written by packw, read by lstm, then
    // y2 is overwritten by conv2 long after lstm completes):
    h2* w16f = (h2*)y2;               //  8,192 u32
    h2* w16r = (h2*)(y2 + 8192);      //  8,192 u32

    // 0) pack Whh to fp16 pairs
    packw_kernel<<<dim3(1), 256, 0, stream>>>(whf, whr, w16f, w16r);
    // 1) input projections (dir-split) + zero BN1/BN2/BN3 stats
    xg_kernel<<<dim3(65, 32, 2), 256, 0, stream>>>(x, wif, bf, wir, br, xg_f, xg_r,
                                                   stats, stats2);
    // 2) bidirectional LSTM recurrence -> X (unit-split, shfl gate exchange)
    lstm_kernel<<<dim3(64), 128, 0, stream>>>(xg_f, xg_r, w16f, w16r, X);
    // 3) wave module -> wave (raw), fused BN1 partial stats
    wave_kernel<<<dim3(3, CCH, B_), 256, 0, stream>>>(X, bw, bb, wave, stats);
    bn1_finalize_kernel<<<dim3(1), 768, 0, stream>>>(stats, m1, r1);
    // 4) fold BN1 into conv2 weights; conv2 on raw wave (+BN2 stats)
    bnfold2_kernel<<<dim3(128), 256, 0, stream>>>(w2, b2, m1, r1, g1, be1, w2t, b2t);
    conv2_kernel<<<dim3(32, 3, 8), 256, 0, stream>>>(wave, w2t, b2t, y2, stats2);
    // 5) fold BN2 (inline finalize) into conv3; conv3 (+BN3 stats)
    bnfold3_kernel<<<dim3(32), 256, 0, stream>>>(w3, b3, stats2, g2, be2, w3t, b3t);
    conv3_kernel<<<dim3(32, 2, 4), 256, 0, stream>>>(y2, w3t, b3t, y3, stats3);
    // 6) fold BN3 (inline finalize) into conv4 weights
    bnfold4_kernel<<<dim3(16), 128, 0, stream>>>(w4, b4, stats3, g3, be3, w4t, b4t);
    // 7) fused conv4 + DWT + conv5 + per-(b,ch) stats (no y4/y5 materialization)
    tail_fused_kernel<<<dim3(B_), 512, 0, stream>>>(y3, w4t, b4t, w5, b5,
                                                    stats3, g3, be3, tpart);
    // 8) BN4/BN5 stats + pooling + FC
    tail_final_kernel<<<dim3(1), 512, 0, stream>>>(tpart, g4, be4, g5, be5, fcw, fcb, out);
}

// Round 13
// 868.604 us; speedup vs baseline: 1.2103x; 1.0009x over previous
//
#include <hip/hip_runtime.h>
#include <math.h>

// Problem constants
#define B_     32
#define F_     64
#define T_     518
#define HID    64
#define GATES  256   // 4*HID
#define CCH    128   // 2*HID lstm output channels
#define NWAVE  6
#define WCH    768   // NWAVE*CCH
#define L2_    516   // T-2   (conv2 out)
#define L3_    512   // L2-4  (conv3 out)
#define L4_    510   // L3-2  (conv4/conv5 out)

typedef float v2f __attribute__((ext_vector_type(2)));
typedef _Float16 h2 __attribute__((ext_vector_type(2)));

__device__ __forceinline__ float frcp(float x) { return __builtin_amdgcn_rcpf(x); }
__device__ __forceinline__ float fsigmoid(float x) { return frcp(1.f + __expf(-x)); }
__device__ __forceinline__ float ftanh(float x) { return 1.f - 2.f * frcp(1.f + __expf(2.f * x)); }

__device__ __forceinline__ float fdot2(h2 a, h2 b, float c) {
#if __has_builtin(__builtin_amdgcn_fdot2)
    return __builtin_amdgcn_fdot2(a, b, c, false);
#else
    return fmaf((float)a[0], (float)b[0], fmaf((float)a[1], (float)b[1], c));
#endif
}

// ---------------------------------------------------------------------------
// K1: input projections, dir-split (grid z = dir). Block (0,0,0) additionally
// zeroes the BN stats buffers and packs Whh->fp16 (absorbs old packw kernel;
// lstm launches strictly after xg so ordering is safe).
__global__ void xg_kernel(const float* __restrict__ x,
                          const float* __restrict__ wif, const float* __restrict__ bf,
                          const float* __restrict__ wir, const float* __restrict__ br,
                          const float* __restrict__ whf, const float* __restrict__ whr,
                          float* __restrict__ xg_f, float* __restrict__ xg_r,
                          float* __restrict__ stats, float* __restrict__ stats23,
                          h2* __restrict__ w16f, h2* __restrict__ w16r) {
    if (blockIdx.x == 0 && blockIdx.y == 0 && blockIdx.z == 0) {
        for (int i = threadIdx.x; i < 2 * WCH; i += 256) stats[i] = 0.f;
        if (threadIdx.x < 320) stats23[threadIdx.x] = 0.f;   // 256 BN2 + 64 BN3
        {   // pack Whh (both dirs) to fp16 pairs; one gate-row per thread
            const int row = threadIdx.x;
            const float* sf = whf + (size_t)row * HID;
            const float* sr = whr + (size_t)row * HID;
#pragma unroll
            for (int i = 0; i < 32; ++i) {
                w16f[row * 32 + i] = (h2){(_Float16)sf[2 * i], (_Float16)sf[2 * i + 1]};
                w16r[row * 32 + i] = (h2){(_Float16)sr[2 * i], (_Float16)sr[2 * i + 1]};
            }
        }
    }
    const int dir = blockIdx.z;
    const float* wi = dir ? wir : wif;
    const float* bi = dir ? br : bf;
    float* xgo = dir ? xg_r : xg_f;
    const int tid = threadIdx.x;
    const int wv  = tid >> 7;
    const int g2  = tid & 1;
    const int r   = (tid >> 1) & 63;
    const int g   = (2 * wv + g2) * 64 + r;       // gate row; store offset == tid
    const int b   = blockIdx.y;
    const int t0  = blockIdx.x * 8;
    float4 wa[16];
    const float4* w0 = (const float4*)(wi + g * F_);
#pragma unroll
    for (int i = 0; i < 16; ++i) wa[i] = w0[i];
    const float bv = bi[g];
    for (int tt = 0; tt < 8; ++tt) {
        const int t = t0 + tt;
        if (t >= T_) break;
        const float* xp = x + (size_t)b * F_ * T_ + t;
        float a0 = bv;
#pragma unroll
        for (int i = 0; i < 16; ++i) {
            float x0 = xp[(i * 4 + 0) * T_];
            float x1 = xp[(i * 4 + 1) * T_];
            float x2 = xp[(i * 4 + 2) * T_];
            float x3 = xp[(i * 4 + 3) * T_];
            a0 += wa[i].x * x0 + wa[i].y * x1 + wa[i].z * x2 + wa[i].w * x3;
        }
        xgo[((size_t)b * T_ + t) * GATES + tid] = a0;   // coalesced
    }
}

// ---------------------------------------------------------------------------
// K2: LSTM recurrence — UNIT-SPLIT 2-wave structure (measured plateau:
// ~560 ns/step across all structures; serial chain bound). FROZEN.
// grid(64), block 128.
__global__ __launch_bounds__(128, 1) void lstm_kernel(
        const float* __restrict__ xgi_f, const float* __restrict__ xgi_r,
        const h2* __restrict__ w16f, const h2* __restrict__ w16r,
        float* __restrict__ X) {
    const int dir = blockIdx.x & 1;
    const int b   = blockIdx.x >> 1;
    const float* xg  = (dir ? xgi_r : xgi_f) + (size_t)b * T_ * GATES;
    const h2* w16 = dir ? w16r : w16f;
    const int tid = threadIdx.x;
    const int lw  = tid & 63;            // lane in wave
    const int w   = tid >> 6;            // wave id
    const int p   = lw >> 5;             // gate-pair: 0 -> (i,f), 1 -> (g,o)
    const int u   = 32 * w + (lw & 31);  // unit owned

    union U4 { uint4 u4; h2 h[4]; };
    U4 wA[8], wB[8];                     // rows (2p)*64+u and (2p+1)*64+u
    {
        const uint4* pA = (const uint4*)(w16 + (size_t)((2 * p) * HID + u) * 32);
        const uint4* pB = (const uint4*)(w16 + (size_t)((2 * p + 1) * HID + u) * 32);
#pragma unroll
        for (int i = 0; i < 8; ++i) { wA[i].u4 = pA[i]; wB[i].u4 = pB[i]; }
    }

    __shared__ __align__(16) _Float16 hs16[2][HID];   // double-buffered h
    if (lw < 32) { hs16[0][u] = (_Float16)0.f; hs16[1][u] = (_Float16)0.f; }
    float c = 0.f;
    float* Xrow = X + ((size_t)(b * CCH + dir * HID + u)) * T_;

    int t = dir ? (T_ - 1) : 0;
    const int step = dir ? -1 : 1;
    const float2* xg2 = (const float2*)xg;   // index (t*2 + p)*64 + u
    float2 q0 = xg2[((size_t)t * 2 + p) * 64 + u];
    float2 q1 = xg2[((size_t)(t + step) * 2 + p) * 64 + u];
    __syncthreads();

    for (int s = 0; s < T_; ++s) {
        const uint4* hp4 = (const uint4*)hs16[(s + 1) & 1];   // prev step's h
        float a0 = q0.x, a0b = 0.f;
        float a1 = q0.y, a1b = 0.f;
#pragma unroll
        for (int i = 0; i < 8; ++i) {
            U4 hv; hv.u4 = hp4[i];
            a0  = fdot2(wA[i].h[0], hv.h[0], a0);
            a0b = fdot2(wA[i].h[1], hv.h[1], a0b);
            a0  = fdot2(wA[i].h[2], hv.h[2], a0);
            a0b = fdot2(wA[i].h[3], hv.h[3], a0b);
            a1  = fdot2(wB[i].h[0], hv.h[0], a1);
            a1b = fdot2(wB[i].h[1], hv.h[1], a1b);
            a1  = fdot2(wB[i].h[2], hv.h[2], a1);
            a1b = fdot2(wB[i].h[3], hv.h[3], a1b);
        }
        const float gA = a0 + a0b;    // gate (2p)*64+u
        const float gB = a1 + a1b;    // gate (2p+1)*64+u
        const float oA = __shfl_xor(gA, 32, 64);
        const float oB = __shfl_xor(gB, 32, 64);
        const float gi = p ? oA : gA;
        const float gf = p ? oB : gB;
        const float gg = p ? gA : oA;
        const float go = p ? gB : oB;

        // prefetch next xg before the dependent tail
        int tp = t + 2 * step;
        tp = tp < 0 ? 0 : (tp >= T_ ? T_ - 1 : tp);
        const float2 qn = xg2[((size_t)tp * 2 + p) * 64 + u];

        const float si = fsigmoid(gi);
        const float sf = fsigmoid(gf);
        const float so = fsigmoid(go);
        c = sf * c + si * ftanh(gg);
        const float h = so * ftanh(c);

        if (lw < 32) { hs16[s & 1][u] = (_Float16)h; Xrow[t] = h; }
        asm volatile("s_waitcnt lgkmcnt(0)" ::: "memory");
        __builtin_amdgcn_s_barrier();

        q0 = q1; q1 = qn;
        t += step;
    }
}

// ---------------------------------------------------------------------------
// K3: wave module + fused BN1 partial stats. Chebyshev cos recurrence.
// grid(3, 128, 32), block 256
__global__ void wave_kernel(const float* __restrict__ X,
                            const float* __restrict__ bw, const float* __restrict__ bb,
                            float* __restrict__ wave, float* __restrict__ stats) {
    const int b = blockIdx.z, c = blockIdx.y;
    const int t0 = blockIdx.x * 256;
    const int tid = threadIdx.x;
    __shared__ float xs[256 + 14];
    __shared__ float bws[NWAVE][16];
    __shared__ float bbs[NWAVE];
    __shared__ float red[4][12];
    const float* xrow = X + ((size_t)(b * CCH + c)) * T_;
    for (int i = tid; i < 270; i += 256) {
        int tt = t0 - 7 + i;
        xs[i] = (tt >= 0 && tt < T_) ? xrow[tt] : 0.f;
    }
    if (tid < NWAVE * 15) bws[tid / 15][tid % 15] = bw[tid];
    if (tid < NWAVE) bbs[tid] = bb[tid];
    __syncthreads();
    const int t = t0 + tid;
    float ls[NWAVE], lq[NWAVE];
#pragma unroll
    for (int ii = 0; ii < NWAVE; ++ii) { ls[ii] = 0.f; lq[ii] = 0.f; }
    if (t < T_) {
        float win[15];
#pragma unroll
        for (int k = 0; k < 15; ++k) win[k] = xs[tid + k];
        float e[8];
        e[0] = win[7];
#pragma unroll
        for (int m = 1; m < 8; ++m) e[m] = win[7 - m] + win[7 + m];
        const float c0 = 6.28318530717958647692f / 15.f;  // 2*pi/WIDE
#pragma unroll
        for (int ii = 0; ii < NWAVE; ++ii) {
            float sc = bbs[ii];
#pragma unroll
            for (int k = 0; k < 15; ++k) sc += win[k] * bws[ii][k];
            sc = fmaxf(sc, 0.f);
            const float phi = c0 * (float)(ii + 1) * sc;
            const float c1 = __cosf(phi);
            float o = fmaf(e[1], c1, e[0]);
            float cp = 1.f, cc = c1;
#pragma unroll
            for (int m = 2; m < 8; ++m) {
                const float cn = fmaf(2.f * c1, cc, -cp);   // cos(m*phi)
                o = fmaf(e[m], cn, o);
                cp = cc; cc = cn;
            }
            const float q = (truncf(sc * 15.f) + 1.f) * (2.f / 17.f);
            const float val = o * rsqrtf(q);
            wave[((size_t)(b * WCH + ii * CCH + c)) * T_ + t] = val;
            ls[ii] = val;
            lq[ii] = val * val;
        }
    }
#pragma unroll
    for (int off = 32; off > 0; off >>= 1) {
#pragma unroll
        for (int ii = 0; ii < NWAVE; ++ii) {
            ls[ii] += __shfl_down(ls[ii], off);
            lq[ii] += __shfl_down(lq[ii], off);
        }
    }
    if ((tid & 63) == 0) {
        const int w = tid >> 6;
#pragma unroll
        for (int ii = 0; ii < NWAVE; ++ii) { red[w][ii] = ls[ii]; red[w][6 + ii] = lq[ii]; }
    }
    __syncthreads();
    if (tid < 12) {
        const float a = red[0][tid] + red[1][tid] + red[2][tid] + red[3][tid];
        const int ii = tid % 6;
        const int ch = ii * CCH + c;
        atomicAdd(&stats[(tid >= 6 ? WCH : 0) + ch], a);
    }
}

// ---------------------------------------------------------------------------
// bnfold2 (BN1 finalize inline from raw stats): grid(128), block 256
__global__ void bnfold2_kernel(const float* __restrict__ w2, const float* __restrict__ b2,
                               const float* __restrict__ stats,
                               const float* __restrict__ g1, const float* __restrict__ be1,
                               float* __restrict__ w2t, float* __restrict__ b2t) {
    const int o = blockIdx.x, tid = threadIdx.x;
    __shared__ float sc1s[WCH], sh1s[WCH];
    for (int c = tid; c < WCH; c += 256) {
        const float n = (float)(B_ * T_);
        const float m = stats[c] / n;
        const float v = stats[WCH + c] / n - m * m;
        const float sc = rsqrtf(v + 1e-5f) * g1[c];
        sc1s[c] = sc;
        sh1s[c] = be1[c] - m * sc;
    }
    __syncthreads();
    float part = 0.f;
    for (int idx = tid; idx < WCH * 3; idx += 256) {
        const int c = idx / 3;
        const float wv = w2[(size_t)o * (WCH * 3) + idx];
        w2t[(size_t)idx * 128 + o] = wv * sc1s[c];
        part += wv * sh1s[c];
    }
#pragma unroll
    for (int off = 32; off > 0; off >>= 1) part += __shfl_down(part, off);
    __shared__ float red[4];
    if ((tid & 63) == 0) red[tid >> 6] = part;
    __syncthreads();
    if (tid == 0) b2t[o] = b2[o] + red[0] + red[1] + red[2] + red[3];
}

// bnfold3 (BN2 finalize inline from raw stats2): grid(32), block 256
__global__ void bnfold3_kernel(const float* __restrict__ w3, const float* __restrict__ b3,
                               const float* __restrict__ stats2,
                               const float* __restrict__ g2, const float* __restrict__ be2,
                               float* __restrict__ w3t, float* __restrict__ b3t) {
    const int o = blockIdx.x, tid = threadIdx.x;
    __shared__ float sc2s[128], sh2s[128];
    if (tid < 128) {
        const float n = (float)(B_ * L2_);
        const float m = stats2[tid] / n;
        const float v = stats2[128 + tid] / n - m * m;
        const float sc = rsqrtf(v + 1e-5f) * g2[tid];
        sc2s[tid] = sc;
        sh2s[tid] = be2[tid] - m * sc;
    }
    __syncthreads();
    float part = 0.f;
    for (int idx = tid; idx < 128 * 5; idx += 256) {
        const int c = idx / 5;
        const float wv = w3[(size_t)o * 640 + idx];
        w3t[(size_t)idx * 32 + o] = wv * sc2s[c];
        part += wv * sh2s[c];
    }
#pragma unroll
    for (int off = 32; off > 0; off >>= 1) part += __shfl_down(part, off);
    __shared__ float red[4];
    if ((tid & 63) == 0) red[tid >> 6] = part;
    __syncthreads();
    if (tid == 0) b3t[o] = b3[o] + red[0] + red[1] + red[2] + red[3];
}

// bnfold4 (BN3 finalize inline from raw stats3): grid(16), block 128
__global__ void bnfold4_kernel(const float* __restrict__ w4, const float* __restrict__ b4,
                               const float* __restrict__ stats3,
                               const float* __restrict__ g3, const float* __restrict__ be3,
                               float* __restrict__ w4t, float* __restrict__ b4t) {
    const int o = blockIdx.x, tid = threadIdx.x;
    __shared__ float sc3s[32], sh3s[32];
    if (tid < 32) {
        const float n = (float)(B_ * L3_);
        const float m = stats3[tid] / n;
        const float v = stats3[32 + tid] / n - m * m;
        const float sc = rsqrtf(v + 1e-5f) * g3[tid];
        sc3s[tid] = sc;
        sh3s[tid] = be3[tid] - m * sc;
    }
    __syncthreads();
    float part = 0.f;
    if (tid < 96) {
        const int c = tid / 3;
        const float wv = w4[(size_t)o * 96 + tid];
        w4t[(size_t)tid * 16 + o] = wv * sc3s[c];
        part = wv * sh3s[c];
    }
#pragma unroll
    for (int off = 32; off > 0; off >>= 1) part += __shfl_down(part, off);
    __shared__ float red[2];
    if ((tid & 63) == 0) red[tid >> 6] = part;
    __syncthreads();
    if (tid == 0) b4t[o] = b4[o] + red[0] + red[1];
}

// ---------------------------------------------------------------------------
// conv2 (BN1 folded) + fused BN2 partial stats: 16-ch/thread (proven shape).
// grid(32 b, 3 t, 8 o), block 256.
__global__ __launch_bounds__(256) void conv2_kernel(
        const float* __restrict__ in, const float* __restrict__ wt,
        const float* __restrict__ bt, float* __restrict__ out,
        float* __restrict__ stats2) {
    const int b  = blockIdx.x;
    const int tid = threadIdx.x;
    const int t  = blockIdx.y * 256 + tid;
    const int o0 = blockIdx.z * 16;
    float rv[16], qv[16];
#pragma unroll
    for (int j = 0; j < 16; ++j) rv[j] = 0.f;
    if (t < L2_) {
        v2f acc[8];
        const v2f* bt2 = (const v2f*)(bt + o0);
#pragma unroll
        for (int j = 0; j < 8; ++j) acc[j] = bt2[j];
        const float* inb = in + (size_t)b * WCH * T_ + t;
        for (int c = 0; c < WCH; ++c) {
            const float x0 = inb[c * T_], x1 = inb[c * T_ + 1], x2 = inb[c * T_ + 2];
            const v2f vx0 = {x0, x0}, vx1 = {x1, x1}, vx2 = {x2, x2};
            const v2f* wc = (const v2f*)(wt + (size_t)c * 384 + o0);  // k-stride 64 v2f
#pragma unroll
            for (int j = 0; j < 8; ++j)
                acc[j] = __builtin_elementwise_fma(wc[j], vx0,
                         __builtin_elementwise_fma(wc[64 + j], vx1,
                         __builtin_elementwise_fma(wc[128 + j], vx2, acc[j])));
        }
        const size_t ob = ((size_t)b * 128 + o0) * L2_ + t;
#pragma unroll
        for (int j = 0; j < 8; ++j) {
            rv[2 * j]     = fmaxf(acc[j].x, 0.f);
            rv[2 * j + 1] = fmaxf(acc[j].y, 0.f);
            out[ob + (size_t)(2 * j) * L2_]     = rv[2 * j];
            out[ob + (size_t)(2 * j + 1) * L2_] = rv[2 * j + 1];
        }
    }
#pragma unroll
    for (int j = 0; j < 16; ++j) qv[j] = rv[j] * rv[j];
#pragma unroll
    for (int off = 32; off > 0; off >>= 1) {
#pragma unroll
        for (int j = 0; j < 16; ++j) {
            rv[j] += __shfl_down(rv[j], off);
            qv[j] += __shfl_down(qv[j], off);
        }
    }
    __shared__ float red2[4][32];
    if ((tid & 63) == 0) {
        const int wv = tid >> 6;
#pragma unroll
        for (int j = 0; j < 16; ++j) { red2[wv][j] = rv[j]; red2[wv][16 + j] = qv[j]; }
    }
    __syncthreads();
    if (tid < 32) {
        const float a = red2[0][tid] + red2[1][tid] + red2[2][tid] + red2[3][tid];
        atomicAdd(&stats2[(tid >= 16 ? 128 : 0) + o0 + (tid & 15)], a);
    }
}

// conv3 (BN2 folded) + fused BN3 partial stats: 16-ch/thread (mirrors conv2's
// proven register shape; halves y2 re-reads). grid(32 b, 2 t, 2 o), block 256.
__global__ __launch_bounds__(256) void conv3_kernel(
        const float* __restrict__ in, const float* __restrict__ wt,
        const float* __restrict__ bt, float* __restrict__ out,
        float* __restrict__ stats3) {
    const int b  = blockIdx.x;
    const int tid = threadIdx.x;
    const int t  = blockIdx.y * 256 + tid;   // < 512 always
    const int o0 = blockIdx.z * 16;
    v2f acc[8];
    const v2f* bt2 = (const v2f*)(bt + o0);
#pragma unroll
    for (int j = 0; j < 8; ++j) acc[j] = bt2[j];
    const float* inb = in + (size_t)b * 128 * L2_ + t;
    for (int c = 0; c < 128; ++c) {
        const float x0 = inb[c * L2_], x1 = inb[c * L2_ + 1], x2 = inb[c * L2_ + 2];
        const float x3 = inb[c * L2_ + 3], x4 = inb[c * L2_ + 4];
        const v2f vx0 = {x0, x0}, vx1 = {x1, x1}, vx2 = {x2, x2}, vx3 = {x3, x3}, vx4 = {x4, x4};
        const v2f* wc = (const v2f*)(wt + (size_t)c * 160 + o0);  // k-stride 16 v2f
#pragma unroll
        for (int j = 0; j < 8; ++j)
            acc[j] = __builtin_elementwise_fma(wc[j], vx0,
                     __builtin_elementwise_fma(wc[16 + j], vx1,
                     __builtin_elementwise_fma(wc[32 + j], vx2,
                     __builtin_elementwise_fma(wc[48 + j], vx3,
                     __builtin_elementwise_fma(wc[64 + j], vx4, acc[j])))));
    }
    const size_t ob = ((size_t)b * 32 + o0) * L3_ + t;
    float rv[16], qv[16];
#pragma unroll
    for (int j = 0; j < 8; ++j) {
        rv[2 * j]     = fmaxf(acc[j].x, 0.f);
        rv[2 * j + 1] = fmaxf(acc[j].y, 0.f);
        out[ob + (size_t)(2 * j) * L3_]     = rv[2 * j];
        out[ob + (size_t)(2 * j + 1) * L3_] = rv[2 * j + 1];
    }
#pragma unroll
    for (int j = 0; j < 16; ++j) qv[j] = rv[j] * rv[j];
#pragma unroll
    for (int off = 32; off > 0; off >>= 1) {
#pragma unroll
        for (int j = 0; j < 16; ++j) {
            rv[j] += __shfl_down(rv[j], off);
            qv[j] += __shfl_down(qv[j], off);
        }
    }
    __shared__ float red3[4][32];
    if ((tid & 63) == 0) {
        const int wv = tid >> 6;
#pragma unroll
        for (int j = 0; j < 16; ++j) { red3[wv][j] = rv[j]; red3[wv][16 + j] = qv[j]; }
    }
    __syncthreads();
    if (tid < 32) {
        const float a = red3[0][tid] + red3[1][tid] + red3[2][tid] + red3[3][tid];
        atomicAdd(&stats3[(tid >= 16 ? 32 : 0) + o0 + (tid & 15)], a);
    }
}

// ---------------------------------------------------------------------------
// Fused conv4 + BN3-affine DWT + conv5 + per-(b,ch) stats. y4/y5 never
// materialized. grid(32), block 512.
__global__ __launch_bounds__(512) void tail_fused_kernel(
        const float* __restrict__ y3, const float* __restrict__ w4t,
        const float* __restrict__ b4t, const float* __restrict__ w5,
        const float* __restrict__ b5, const float* __restrict__ stats3,
        const float* __restrict__ g3, const float* __restrict__ be3,
        float* __restrict__ part) {
    const int b = blockIdx.x, l = threadIdx.x;  // l in [0,512)
    __shared__ float cm[L3_];
    __shared__ float bands[5][L3_];
    __shared__ float w5s[240];
    __shared__ float b5s[16], b4s[16];
    __shared__ float sc3s[32], sh3s[32];
    __shared__ float redf[8][64];
    if (l < 240) w5s[l] = w5[l];
    if (l < 16) { b5s[l] = b5[l]; b4s[l] = b4t[l]; }
    if (l >= 256 && l < 288) {
        const int ch = l - 256;
        const float n = (float)(B_ * L3_);
        const float m = stats3[ch] / n;
        const float v = stats3[32 + ch] / n - m * m;
        const float sc = rsqrtf(v + 1e-5f) * g3[ch];
        sc3s[ch] = sc;
        sh3s[ch] = be3[ch] - m * sc;
    }
    __syncthreads();
    v2f a4[8];
    const v2f* b4s2 = (const v2f*)b4s;
#pragma unroll
    for (int j = 0; j < 8; ++j) a4[j] = (v2f){0.f, 0.f};
    const float* yb = y3 + (size_t)b * 32 * L3_ + l;
    if (l < L4_) {
#pragma unroll
        for (int j = 0; j < 8; ++j) a4[j] = b4s2[j];
        for (int c = 0; c < 32; ++c) {
            const float x0 = yb[c * L3_], x1 = yb[c * L3_ + 1], x2 = yb[c * L3_ + 2];
            const v2f vx0 = {x0, x0}, vx1 = {x1, x1}, vx2 = {x2, x2};
            const v2f* wc = (const v2f*)(w4t + (size_t)c * 48);   // k-stride 8 v2f
#pragma unroll
            for (int j = 0; j < 8; ++j)
                a4[j] = __builtin_elementwise_fma(wc[j], vx0,
                        __builtin_elementwise_fma(wc[8 + j], vx1,
                        __builtin_elementwise_fma(wc[16 + j], vx2, a4[j])));
        }
    }
    {
        float s = 0.f, shs = 0.f;
        for (int ch = 0; ch < 32; ++ch) {
            s = fmaf(yb[ch * L3_], sc3s[ch], s);
            shs += sh3s[ch];
        }
        cm[l] = (s + shs) * (1.f / 32.f);
    }
    __syncthreads();
    const float s1 = 0.70710678118654752440f;
    const float s2c = 0.5f;
    const float s3 = 0.35355339059327378f;
    const float s4 = 0.25f;
    const int b16 = l & ~15, b8 = l & ~7, b4v = l & ~3, b2v = l & ~1;
    float sa = 0.f, sb = 0.f;
#pragma unroll
    for (int i = 0; i < 8; ++i) { sa += cm[b16 + i]; sb += cm[b16 + 8 + i]; }
    bands[0][l] = (sa + sb) * s4;
    bands[1][l] = (sa - sb) * s4;
    float ta = 0.f, tb = 0.f;
#pragma unroll
    for (int i = 0; i < 4; ++i) { ta += cm[b8 + i]; tb += cm[b8 + 4 + i]; }
    bands[2][l] = (ta - tb) * s3;
    bands[3][l] = (cm[b4v] + cm[b4v + 1] - cm[b4v + 2] - cm[b4v + 3]) * s2c;
    bands[4][l] = (cm[b2v] - cm[b2v + 1]) * s1;
    __syncthreads();
    float s4v[16], q4v[16], s5v[16], q5v[16];
#pragma unroll
    for (int o = 0; o < 16; ++o) { s5v[o] = 0.f; }
    if (l < L4_) {
        float in3[5][3];
#pragma unroll
        for (int c = 0; c < 5; ++c) {
            in3[c][0] = bands[c][l]; in3[c][1] = bands[c][l + 1]; in3[c][2] = bands[c][l + 2];
        }
#pragma unroll
        for (int o = 0; o < 16; ++o) {
            float acc = b5s[o];
#pragma unroll
            for (int c = 0; c < 5; ++c) {
                const float* wp = &w5s[(o * 5 + c) * 3];
                acc += in3[c][0] * wp[0] + in3[c][1] * wp[1] + in3[c][2] * wp[2];
            }
            s5v[o] = fmaxf(acc, 0.f);
        }
    }
#pragma unroll
    for (int j = 0; j < 8; ++j) {
        const float v0 = (l < L4_) ? fmaxf(a4[j].x, 0.f) : 0.f;
        const float v1 = (l < L4_) ? fmaxf(a4[j].y, 0.f) : 0.f;
        s4v[2 * j] = v0; s4v[2 * j + 1] = v1;
        q4v[2 * j] = v0 * v0; q4v[2 * j + 1] = v1 * v1;
    }
#pragma unroll
    for (int o = 0; o < 16; ++o) q5v[o] = s5v[o] * s5v[o];
#pragma unroll
    for (int off = 32; off > 0; off >>= 1) {
#pragma unroll
        for (int o = 0; o < 16; ++o) {
            s4v[o] += __shfl_down(s4v[o], off);
            q4v[o] += __shfl_down(q4v[o], off);
            s5v[o] += __shfl_down(s5v[o], off);
            q5v[o] += __shfl_down(q5v[o], off);
        }
    }
    if ((l & 63) == 0) {
        const int wv = l >> 6;
#pragma unroll
        for (int o = 0; o < 16; ++o) {
            redf[wv][o]      = s4v[o];
            redf[wv][16 + o] = q4v[o];
            redf[wv][32 + o] = s5v[o];
            redf[wv][48 + o] = q5v[o];
        }
    }
    __syncthreads();
    if (l < 64) {
        float a = 0.f;
#pragma unroll
        for (int wv = 0; wv < 8; ++wv) a += redf[wv][l];
        part[(size_t)(b * 16 + (l & 15)) * 4 + (l >> 4)] = a;
    }
}

// Tail stage B: BN4/BN5 stats + pooling(+affine) + FC. grid(1), block 512.
__global__ __launch_bounds__(512) void tail_final_kernel(
        const float* __restrict__ part,
        const float* __restrict__ g4, const float* __restrict__ be4,
        const float* __restrict__ g5, const float* __restrict__ be5,
        const float* __restrict__ fcw, const float* __restrict__ fcb,
        float* __restrict__ out) {
    const int p = threadIdx.x;           // 0..511
    const int b = p >> 4, ch = p & 15;
    const float4 v = ((const float4*)part)[b * 16 + ch];  // s4,q4,s5,q5
    __shared__ float S4[512], Q4[512], S5[512], Q5[512];
    __shared__ float M4[16], R4[16], M5[16], R5[16];
    __shared__ float pool[B_][16];
    S4[p] = v.x; Q4[p] = v.y; S5[p] = v.z; Q5[p] = v.w;
    __syncthreads();
    if (p < 16) {
        float ts = 0.f, tq = 0.f, us = 0.f, uq = 0.f;
        for (int bb = 0; bb < B_; ++bb) {
            ts += S4[bb * 16 + p]; tq += Q4[bb * 16 + p];
            us += S5[bb * 16 + p]; uq += Q5[bb * 16 + p];
        }
        const float n = (float)(B_ * L4_);
        float m = ts / n; M4[p] = m; R4[p] = rsqrtf(tq / n - m * m + 1e-5f);
        m = us / n;       M5[p] = m; R5[p] = rsqrtf(uq / n - m * m + 1e-5f);
    }
    __syncthreads();
    {
        const float mm4 = v.x / (float)L4_, mm5 = v.z / (float)L4_;
        const float v4 = (mm4 - M4[ch]) * R4[ch] * g4[ch] + be4[ch];
        const float v5 = (mm5 - M5[ch]) * R5[ch] * g5[ch] + be5[ch];
        pool[b][ch] = 0.5f * (v4 + v5);
    }
    __syncthreads();
    if (p < B_ * 10) {
        const int bb = p / 10, row = p - bb * 10;
        float a = fcb[row];
#pragma unroll
        for (int c = 0; c < 16; ++c) a += pool[bb][c] * fcw[row * 16 + c];
        out[bb * 10 + row] = a;
    }
}

// ---------------------------------------------------------------------------
extern "C" void kernel_launch(void* const* d_in, const int* in_sizes, int n_in,
                              void* d_out, int out_size, void* d_ws, size_t ws_size,
                              hipStream_t stream) {
    (void)in_sizes; (void)n_in; (void)out_size; (void)ws_size;
    const float* x   = (const float*)d_in[0];
    const float* wif = (const float*)d_in[1];
    const float* whf = (const float*)d_in[2];
    const float* bf  = (const float*)d_in[3];
    const float* wir = (const float*)d_in[4];
    const float* whr = (const float*)d_in[5];
    const float* br  = (const float*)d_in[6];
    const float* bw  = (const float*)d_in[7];
    const float* bb  = (const float*)d_in[8];
    const float* g1  = (const float*)d_in[9];  const float* be1 = (const float*)d_in[10];
    const float* g2  = (const float*)d_in[11]; const float* be2 = (const float*)d_in[12];
    const float* g3  = (const float*)d_in[13]; const float* be3 = (const float*)d_in[14];
    const float* g4  = (const float*)d_in[15]; const float* be4 = (const float*)d_in[16];
    const float* g5  = (const float*)d_in[17]; const float* be5 = (const float*)d_in[18];
    const float* w2  = (const float*)d_in[19]; const float* b2  = (const float*)d_in[20];
    const float* w3  = (const float*)d_in[21]; const float* b3  = (const float*)d_in[22];
    const float* w4  = (const float*)d_in[23]; const float* b4  = (const float*)d_in[24];
    const float* w5  = (const float*)d_in[25]; const float* b5  = (const float*)d_in[26];
    const float* fcw = (const float*)d_in[27]; const float* fcb = (const float*)d_in[28];
    float* out = (float*)d_out;
    float* ws  = (float*)d_ws;

    // Workspace layout (floats). xg region is reused by `wave` after the LSTM.
    float* xg_f  = ws;                       //  4,243,456
    float* xg_r  = ws + 4243456;             //  4,243,456
    float* wave  = ws;                       // 12,730,368 (reuses xg region)
    float* X     = ws + 12730368;            //  2,121,728 (dead after wave_kernel)
    float* y2    = ws + 14852096;            //  2,113,536
    float* y3    = ws + 16965632;            //    524,288
    float* stats = ws + 18012160;            //      1,536 (BN1 s/s2)
    float* tpart  = ws + 18013696;           //      2,048 (tail partials)
    float* stats2 = tpart + 2048;            //        256 (BN2 raw s/s2)
    float* stats3 = stats2 + 256;            //         64 (BN3 raw s/s2)
    // Folded weights live in the dead X region (X only read by wave_kernel):
    float* w2t  = X;                  // 294,912
    float* b2t  = X + 294912;         //     128
    float* w3t  = X + 295040;         //  20,480
    float* b3t  = X + 315520;         //      32
    float* w4t  = X + 315552;         //   1,536
    float* b4t  = X + 317088;         //      16
    // fp16 Whh lives in the y2 region (written by xg block 0, read by lstm,
    // y2 overwritten by conv2 long after lstm completes):
    h2* w16f = (h2*)y2;               //  8,192 u32
    h2* w16r = (h2*)(y2 + 8192);      //  8,192 u32

    // 1) input projections (dir-split) + stats zero + Whh fp16 pack
    xg_kernel<<<dim3(65, 32, 2), 256, 0, stream>>>(x, wif, bf, wir, br, whf, whr,
                                                   xg_f, xg_r, stats, stats2,
                                                   w16f, w16r);
    // 2) bidirectional LSTM recurrence -> X (unit-split, shfl gate exchange)
    lstm_kernel<<<dim3(64), 128, 0, stream>>>(xg_f, xg_r, w16f, w16r, X);
    // 3) wave module -> wave (raw), fused BN1 partial stats
    wave_kernel<<<dim3(3, CCH, B_), 256, 0, stream>>>(X, bw, bb, wave, stats);
    // 4) fold BN1 (inline finalize) into conv2; conv2 on raw wave (+BN2 stats)
    bnfold2_kernel<<<dim3(128), 256, 0, stream>>>(w2, b2, stats, g1, be1, w2t, b2t);
    conv2_kernel<<<dim3(32, 3, 8), 256, 0, stream>>>(wave, w2t, b2t, y2, stats2);
    // 5) fold BN2 (inline finalize) into conv3; conv3 (+BN3 stats)
    bnfold3_kernel<<<dim3(32), 256, 0, stream>>>(w3, b3, stats2, g2, be2, w3t, b3t);
    conv3_kernel<<<dim3(32, 2, 2), 256, 0, stream>>>(y2, w3t, b3t, y3, stats3);
    // 6) fold BN3 (inline finalize) into conv4 weights
    bnfold4_kernel<<<dim3(16), 128, 0, stream>>>(w4, b4, stats3, g3, be3, w4t, b4t);
    // 7) fused conv4 + DWT + conv5 + per-(b,ch) stats (no y4/y5 materialization)
    tail_fused_kernel<<<dim3(B_), 512, 0, stream>>>(y3, w4t, b4t, w5, b5,
                                                    stats3, g3, be3, tpart);
    // 8) BN4/BN5 stats + pooling + FC
    tail_final_kernel<<<dim3(1), 512, 0, stream>>>(tpart, g4, be4, g5, be5, fcw, fcb, out);
}